// Round 16
// baseline (412.032 us; speedup 1.0000x reference)
//
#include <hip/hip_runtime.h>
#include <hip/hip_bf16.h>

#define NNODES 50000
#define MT 3125              // NNODES / 16 row-tiles
#define NB 196               // ceil(NNODES / 256) dst-buckets
typedef __hip_bfloat16 bf16;
typedef __attribute__((ext_vector_type(8))) short bf16x8;  // 8 bf16 (4 VGPRs)
typedef __attribute__((ext_vector_type(4))) float f32x4;   // 4 f32 acc

__device__ __forceinline__ void unpack2(unsigned w, float& lo, float& hi){
  lo = __uint_as_float(w << 16);
  hi = __uint_as_float(w & 0xffff0000u);
}
__device__ __forceinline__ short f2bf(float f){
  union { __hip_bfloat16 h; short s; } u; u.h = __float2bfloat16(f); return u.s;
}
__device__ __forceinline__ float lrelu(float v){ return v > 0.f ? v : 0.2f * v; }
__device__ __forceinline__ unsigned fenc(float f){
  unsigned u = __float_as_uint(f);
  return (u & 0x80000000u) ? ~u : (u | 0x80000000u);
}
__device__ __forceinline__ float fdec(unsigned u){
  unsigned b = (u & 0x80000000u) ? (u & 0x7fffffffu) : ~u;
  return __uint_as_float(b);
}

// ---------------- pack weights -> B-fragment bf16 ----------------
__global__ __launch_bounds__(256)
void cvt_w_k(const float* __restrict__ W1, const float* __restrict__ Wmu,
             const float* __restrict__ Wls, bf16x8* __restrict__ Bp1,
             bf16x8* __restrict__ Bp2){
  int t = blockIdx.x * 256 + threadIdx.x;
  if (t < 4096){
    int lane = t & 63, ct = (t >> 6) & 15, kt = t >> 10;
    int k0 = kt * 32 + (lane >> 4) * 8, col = ct * 16 + (lane & 15);
    bf16x8 o;
    #pragma unroll
    for (int j = 0; j < 8; j++) o[j] = f2bf(W1[(size_t)(k0 + j) * 256 + col]);
    Bp1[t] = o;
  } else if (t < 8192){
    int u = t - 4096;
    int lane = u & 63, ct = (u >> 6) & 7, kt = u >> 9;
    int k0 = kt * 32 + (lane >> 4) * 8, col = ct * 16 + (lane & 15);
    const float* W = (col < 64) ? Wmu : Wls;
    int cc = col & 63;
    bf16x8 o;
    #pragma unroll
    for (int j = 0; j < 8; j++) o[j] = f2bf(W[(size_t)(k0 + j) * 64 + cc]);
    Bp2[u] = o;
  }
}

// ------- MFMA GEMM 1 + fused alpha + fused per-head global max (atomicMax) -------
__global__ __launch_bounds__(256)
void gemm1_mfma(const float* __restrict__ x, const bf16x8* __restrict__ Bp,
                const float* __restrict__ aS, const float* __restrict__ aD,
                bf16* __restrict__ Y, float* __restrict__ as1, float* __restrict__ ad1,
                unsigned* __restrict__ gm){
  int rt = blockIdx.x;
  int w = threadIdx.x >> 6, lane = threadIdx.x & 63;
  const float* xr = x + (size_t)(rt * 16 + (lane & 15)) * 128 + (lane >> 4) * 8;
  f32x4 z = {0.f, 0.f, 0.f, 0.f};
  f32x4 acc[4] = {z, z, z, z};
  for (int kt = 0; kt < 4; kt++){
    float4 v0 = *(const float4*)(xr + kt * 32);
    float4 v1 = *(const float4*)(xr + kt * 32 + 4);
    bf16x8 a;
    a[0] = f2bf(v0.x); a[1] = f2bf(v0.y); a[2] = f2bf(v0.z); a[3] = f2bf(v0.w);
    a[4] = f2bf(v1.x); a[5] = f2bf(v1.y); a[6] = f2bf(v1.z); a[7] = f2bf(v1.w);
    #pragma unroll
    for (int c = 0; c < 4; c++){
      bf16x8 b = Bp[(size_t)(kt * 16 + w * 4 + c) * 64 + lane];
      acc[c] = __builtin_amdgcn_mfma_f32_16x16x32_bf16(a, b, acc[c], 0, 0, 0);
    }
  }
  int row0 = rt * 16 + (lane >> 4) * 4;
  #pragma unroll
  for (int c = 0; c < 4; c++){
    int col = w * 64 + c * 16 + (lane & 15);
    #pragma unroll
    for (int i = 0; i < 4; i++)
      Y[(size_t)(row0 + i) * 256 + col] = __float2bfloat16(acc[c][i]);
  }
  float aSv[4], aDv[4];
  #pragma unroll
  for (int c = 0; c < 4; c++){
    int col = c * 16 + (lane & 15);
    aSv[c] = aS[w * 64 + col];
    aDv[c] = aD[w * 64 + col];
  }
  float bm = -1e30f;
  #pragma unroll
  for (int i = 0; i < 4; i++){
    float s1 = 0.f, s2 = 0.f;
    #pragma unroll
    for (int c = 0; c < 4; c++){
      s1 = fmaf(acc[c][i], aSv[c], s1);
      s2 = fmaf(acc[c][i], aDv[c], s2);
    }
    #pragma unroll
    for (int o = 1; o < 16; o <<= 1){
      s1 += __shfl_xor(s1, o);
      s2 += __shfl_xor(s2, o);
    }
    bm = fmaxf(bm, s1);              // butterfly left s1 in all 16 lanes
    if ((lane & 15) == 0){
      int node = row0 + i;
      as1[node * 4 + w] = s1;
      ad1[node * 4 + w] = s2;
    }
  }
  // wave-level max over the 4 col-groups, 1 fire-and-forget atomic per wave
  bm = fmaxf(bm, __shfl_xor(bm, 16));
  bm = fmaxf(bm, __shfl_xor(bm, 32));
  if (lane == 0) atomicMax(&gm[w], fenc(bm));
}

// ------- MFMA GEMM 2: interleaved h2 + fused alphas + fused global max -------
__global__ __launch_bounds__(256)
void gemm2_mfma(const bf16x8* __restrict__ Ap, const bf16x8* __restrict__ Bp,
                const float* __restrict__ aSmu, const float* __restrict__ aDmu,
                const float* __restrict__ aSls, const float* __restrict__ aDls,
                bf16* __restrict__ Y2,
                float* __restrict__ as2m, float* __restrict__ ad2m,
                float* __restrict__ as2l, float* __restrict__ ad2l,
                unsigned* __restrict__ gm){
  int w = threadIdx.x >> 6, lane = threadIdx.x & 63;
  int rt = blockIdx.x * 4 + w;
  if (rt >= MT) return;
  f32x4 z = {0.f, 0.f, 0.f, 0.f};
  f32x4 acc[8] = {z, z, z, z, z, z, z, z};   // 0-3 mu, 4-7 ls
  for (int kt = 0; kt < 8; kt++){
    bf16x8 a = Ap[(size_t)(rt * 8 + kt) * 64 + lane];
    #pragma unroll
    for (int c = 0; c < 8; c++){
      bf16x8 b = Bp[(size_t)(kt * 8 + c) * 64 + lane];
      acc[c] = __builtin_amdgcn_mfma_f32_16x16x32_bf16(a, b, acc[c], 0, 0, 0);
    }
  }
  int row0 = rt * 16 + (lane >> 4) * 4;
  #pragma unroll
  for (int c = 0; c < 4; c++){
    int col = c * 16 + (lane & 15);
    #pragma unroll
    for (int i = 0; i < 4; i++){
      Y2[(size_t)(row0 + i) * 128 + col]       = __float2bfloat16(acc[c][i]);
      Y2[(size_t)(row0 + i) * 128 + 64 + col]  = __float2bfloat16(acc[4 + c][i]);
    }
  }
  float aSm[4], aDm[4], aSl[4], aDl[4];
  #pragma unroll
  for (int c = 0; c < 4; c++){
    int col = c * 16 + (lane & 15);
    aSm[c] = aSmu[col]; aDm[c] = aDmu[col];
    aSl[c] = aSls[col]; aDl[c] = aDls[col];
  }
  float bm1 = -1e30f, bm3 = -1e30f;
  #pragma unroll
  for (int i = 0; i < 4; i++){
    float s1 = 0.f, s2 = 0.f, s3 = 0.f, s4 = 0.f;
    #pragma unroll
    for (int c = 0; c < 4; c++){
      s1 = fmaf(acc[c][i], aSm[c], s1);
      s2 = fmaf(acc[c][i], aDm[c], s2);
      s3 = fmaf(acc[4 + c][i], aSl[c], s3);
      s4 = fmaf(acc[4 + c][i], aDl[c], s4);
    }
    #pragma unroll
    for (int o = 1; o < 16; o <<= 1){
      s1 += __shfl_xor(s1, o);
      s2 += __shfl_xor(s2, o);
      s3 += __shfl_xor(s3, o);
      s4 += __shfl_xor(s4, o);
    }
    bm1 = fmaxf(bm1, s1);
    bm3 = fmaxf(bm3, s3);
    if ((lane & 15) == 0){
      int node = row0 + i;
      as2m[node] = s1; ad2m[node] = s2;
      as2l[node] = s3; ad2l[node] = s4;
    }
  }
  bm1 = fmaxf(bm1, __shfl_xor(bm1, 16));
  bm1 = fmaxf(bm1, __shfl_xor(bm1, 32));
  bm3 = fmaxf(bm3, __shfl_xor(bm3, 16));
  bm3 = fmaxf(bm3, __shfl_xor(bm3, 32));
  if (lane == 0){
    atomicMax(&gm[4], fenc(bm1));
    atomicMax(&gm[5], fenc(bm3));
  }
}

// ================ two-phase LDS bucket CSR build ================
__global__ __launch_bounds__(256)
void bhist_k(const int* __restrict__ ei, int E0, int Etot, int* __restrict__ bcnt){
  __shared__ int lh[NB];
  for (int i = threadIdx.x; i < NB; i += 256) lh[i] = 0;
  __syncthreads();
  int base = blockIdx.x * 1024 + threadIdx.x;
  #pragma unroll
  for (int q = 0; q < 4; q++){
    int e = base + q * 256;
    if (e < Etot){
      int d = (e < E0) ? ei[E0 + e] : e - E0;
      atomicAdd(&lh[d >> 8], 1);
    }
  }
  __syncthreads();
  for (int i = threadIdx.x; i < NB; i += 256)
    if (lh[i]) atomicAdd(&bcnt[i], lh[i]);
}

__global__ __launch_bounds__(256)
void bscan_k(const int* __restrict__ bcnt, int* __restrict__ bbase,
             int* __restrict__ bcur, int total){
  __shared__ int buf[256];
  int t = threadIdx.x;
  int v = (t < NB) ? bcnt[t] : 0;
  buf[t] = v; __syncthreads();
  int acc = v;
  for (int off = 1; off < 256; off <<= 1){
    int x = (t >= off) ? buf[t - off] : 0;
    __syncthreads();
    acc += x; buf[t] = acc; __syncthreads();
  }
  if (t < NB){ int ex = acc - v; bbase[t] = ex; bcur[t] = ex; }
  if (t == 0) bbase[NB] = total;
}

__global__ __launch_bounds__(256)
void bscat_k(const int* __restrict__ ei, int E0, int Etot,
             int* __restrict__ bcur, unsigned* __restrict__ buck){
  __shared__ int lh[NB];
  __shared__ int lbase[NB];
  for (int i = threadIdx.x; i < NB; i += 256) lh[i] = 0;
  __syncthreads();
  int base = blockIdx.x * 1024 + threadIdx.x;
  int sA[4], dA[4], rA[4];
  #pragma unroll
  for (int q = 0; q < 4; q++){
    int e = base + q * 256;
    sA[q] = -1;
    if (e < Etot){
      int s, d;
      if (e < E0){ s = ei[e]; d = ei[E0 + e]; } else { s = d = e - E0; }
      sA[q] = s; dA[q] = d;
      rA[q] = atomicAdd(&lh[d >> 8], 1);
    }
  }
  __syncthreads();
  for (int i = threadIdx.x; i < NB; i += 256)
    lbase[i] = lh[i] ? atomicAdd(&bcur[i], lh[i]) : 0;
  __syncthreads();
  #pragma unroll
  for (int q = 0; q < 4; q++){
    if (sA[q] >= 0){
      int bk = dA[q] >> 8;
      buck[lbase[bk] + rA[q]] = ((unsigned)(dA[q] & 255) << 16) | (unsigned)sA[q];
    }
  }
}

__global__ __launch_bounds__(256)
void bcsr_k(const unsigned* __restrict__ buck, const int* __restrict__ bbase,
            int* __restrict__ offs, int* __restrict__ srcs, int n){
  int b = blockIdx.x;
  int lo = bbase[b], hi = bbase[b + 1];
  __shared__ int eh[256];
  __shared__ int buf[256];
  int t = threadIdx.x;
  eh[t] = 0;
  __syncthreads();
  for (int j = lo + t; j < hi; j += 256)
    atomicAdd(&eh[(buck[j] >> 16) & 255], 1);
  __syncthreads();
  int v = eh[t];
  buf[t] = v; __syncthreads();
  int acc = v;
  for (int off = 1; off < 256; off <<= 1){
    int x = (t >= off) ? buf[t - off] : 0;
    __syncthreads();
    acc += x; buf[t] = acc; __syncthreads();
  }
  int loff = acc - v;   // exclusive within bucket
  int node = b * 256 + t;
  if (node < n) offs[node] = lo + loff;
  if (b == NB - 1 && t == 0) offs[n] = bbase[NB];
  __syncthreads();
  eh[t] = loff;        // reuse as cursors
  __syncthreads();
  for (int j = lo + t; j < hi; j += 256){
    unsigned val = buck[j];
    int dlo = (val >> 16) & 255;
    int rank = atomicAdd(&eh[dlo], 1);
    srcs[lo + rank] = (int)(val & 0xffffu);
  }
}

// ------- aggregation layer 1: 2 nodes/block, GLOBAL max bound (no pass A) -------
// pass2: slot = lane>>5 (2), head = (lane>>3)&3, oct = lane&7  (R15 form, VGPR 20)
__global__ __launch_bounds__(128)
void gat_aggr1_k(const int* __restrict__ offs, const int* __restrict__ srcs,
                 const float* __restrict__ as, const float* __restrict__ ad,
                 const unsigned* __restrict__ gm,
                 const bf16* __restrict__ h, const float* __restrict__ b,
                 bf16x8* __restrict__ Ap2, int n){
  int node = blockIdx.x * 2 + (threadIdx.x >> 6);
  if (node >= n) return;
  int lane = threadIdx.x & 63;
  int beg = offs[node], end = offs[node + 1];
  int hP = (lane >> 3) & 3, oct = lane & 7, slot = lane >> 5;
  float advP = ad[node * 4 + hP];
  float mP = lrelu(fdec(gm[hP]) + advP);   // upper bound on every edge logit
  float s = 0.f;
  float acc[8];
  #pragma unroll
  for (int i = 0; i < 8; i++) acc[i] = 0.f;
  #pragma unroll 8
  for (int j0 = beg; j0 < end; j0 += 2){
    int j = j0 + slot;
    if (j < end){
      int si = srcs[j];
      float e = lrelu(as[si * 4 + hP] + advP);
      float p = __expf(e - mP);
      s += p;
      uint4 dw = *(const uint4*)(h + (size_t)si * 256 + hP * 64 + oct * 8);
      float lo, hi;
      unpack2(dw.x, lo, hi); acc[0] = fmaf(lo, p, acc[0]); acc[1] = fmaf(hi, p, acc[1]);
      unpack2(dw.y, lo, hi); acc[2] = fmaf(lo, p, acc[2]); acc[3] = fmaf(hi, p, acc[3]);
      unpack2(dw.z, lo, hi); acc[4] = fmaf(lo, p, acc[4]); acc[5] = fmaf(hi, p, acc[5]);
      unpack2(dw.w, lo, hi); acc[6] = fmaf(lo, p, acc[6]); acc[7] = fmaf(hi, p, acc[7]);
    }
  }
  s += __shfl_xor(s, 32);
  #pragma unroll
  for (int i = 0; i < 8; i++) acc[i] += __shfl_xor(acc[i], 32);
  if (lane < 32){
    float inv = 1.f / (s + 1e-16f);
    bf16x8 o;
    #pragma unroll
    for (int i = 0; i < 8; i++){
      float vv = acc[i] * inv + b[lane * 8 + i];
      o[i] = f2bf(vv > 0.f ? vv : 0.f);
    }
    int kt = lane >> 2, g = lane & 3;
    int rt = node >> 4, r = node & 15;
    Ap2[(size_t)(rt * 8 + kt) * 64 + g * 16 + r] = o;
  }
}

// ------- aggregation mu & logstd: interleaved h2, GLOBAL max, guard-free bulk -------
// pass2: slot = lane>>4 (4), branch = (lane>>3)&1, oct = lane&7  (R13 loop form)
__global__ __launch_bounds__(128)
void gat_aggr2_k(const int* __restrict__ offs, const int* __restrict__ srcs,
                 const float* __restrict__ as2m, const float* __restrict__ ad2m,
                 const float* __restrict__ as2l, const float* __restrict__ ad2l,
                 const unsigned* __restrict__ gm,
                 const bf16* __restrict__ h2,
                 const float* __restrict__ bmu, const float* __restrict__ bls,
                 float* __restrict__ outmu, float* __restrict__ outls, int n){
  int node = blockIdx.x * 2 + (threadIdx.x >> 6);
  if (node >= n) return;
  int lane = threadIdx.x & 63;
  int beg = offs[node], end = offs[node + 1];
  int deg = end - beg;
  int br = (lane >> 3) & 1, oct = lane & 7, slot = lane >> 4;
  const float* asP = br ? as2l : as2m;
  float advP = (br ? ad2l : ad2m)[node];
  float mP = lrelu(fdec(gm[4 + br]) + advP);
  float s = 0.f;
  float acc[8];
  #pragma unroll
  for (int i = 0; i < 8; i++) acc[i] = 0.f;
  int bulk = beg + (deg & ~3);
  #pragma unroll 4
  for (int j0 = beg; j0 < bulk; j0 += 4){
    int si = srcs[j0 + slot];
    float e = lrelu(asP[si] + advP);
    float p = __expf(e - mP);
    s += p;
    uint4 dw = *(const uint4*)(h2 + (size_t)si * 128 + br * 64 + oct * 8);
    float lo, hi;
    unpack2(dw.x, lo, hi); acc[0] = fmaf(lo, p, acc[0]); acc[1] = fmaf(hi, p, acc[1]);
    unpack2(dw.y, lo, hi); acc[2] = fmaf(lo, p, acc[2]); acc[3] = fmaf(hi, p, acc[3]);
    unpack2(dw.z, lo, hi); acc[4] = fmaf(lo, p, acc[4]); acc[5] = fmaf(hi, p, acc[5]);
    unpack2(dw.w, lo, hi); acc[6] = fmaf(lo, p, acc[6]); acc[7] = fmaf(hi, p, acc[7]);
  }
  {
    int j = bulk + slot;
    if (j < end){
      int si = srcs[j];
      float e = lrelu(asP[si] + advP);
      float p = __expf(e - mP);
      s += p;
      uint4 dw = *(const uint4*)(h2 + (size_t)si * 128 + br * 64 + oct * 8);
      float lo, hi;
      unpack2(dw.x, lo, hi); acc[0] = fmaf(lo, p, acc[0]); acc[1] = fmaf(hi, p, acc[1]);
      unpack2(dw.y, lo, hi); acc[2] = fmaf(lo, p, acc[2]); acc[3] = fmaf(hi, p, acc[3]);
      unpack2(dw.z, lo, hi); acc[4] = fmaf(lo, p, acc[4]); acc[5] = fmaf(hi, p, acc[5]);
      unpack2(dw.w, lo, hi); acc[6] = fmaf(lo, p, acc[6]); acc[7] = fmaf(hi, p, acc[7]);
    }
  }
  #pragma unroll
  for (int off = 16; off <= 32; off <<= 1){
    s += __shfl_xor(s, off);
    #pragma unroll
    for (int i = 0; i < 8; i++) acc[i] += __shfl_xor(acc[i], off);
  }
  if (lane < 16){
    float inv = 1.f / (s + 1e-16f);
    const float* bb = (lane >= 8) ? bls : bmu;
    float* out = (lane >= 8) ? outls : outmu;
    float v[8];
    #pragma unroll
    for (int i = 0; i < 8; i++) v[i] = acc[i] * inv + bb[oct * 8 + i];
    float* op = out + (size_t)node * 64 + oct * 8;
    *(float4*)op       = make_float4(v[0], v[1], v[2], v[3]);
    *(float4*)(op + 4) = make_float4(v[4], v[5], v[6], v[7]);
  }
}

extern "C" void kernel_launch(void* const* d_in, const int* in_sizes, int n_in,
                              void* d_out, int out_size, void* d_ws, size_t ws_size,
                              hipStream_t stream){
  const float* x    = (const float*)d_in[0];
  const int*   ei   = (const int*)d_in[1];
  const float* W1   = (const float*)d_in[2];
  const float* aS1  = (const float*)d_in[3];
  const float* aD1  = (const float*)d_in[4];
  const float* b1   = (const float*)d_in[5];
  const float* Wmu  = (const float*)d_in[6];
  const float* aSmu = (const float*)d_in[7];
  const float* aDmu = (const float*)d_in[8];
  const float* bmu  = (const float*)d_in[9];
  const float* Wls  = (const float*)d_in[10];
  const float* aSls = (const float*)d_in[11];
  const float* aDls = (const float*)d_in[12];
  const float* bls  = (const float*)d_in[13];

  const int N    = NNODES;
  const int E0   = in_sizes[1] / 2;
  const int Etot = E0 + N;

  // ---- workspace layout (float-unit offsets; bf16x8 arrays 16B-aligned) ----
  float* ws = (float*)d_ws;
  bf16x8* Ap2  = (bf16x8*)(ws);                 // [0, 6.4M): layer-1 out, packed A-frag
  bf16*   h1bf = (bf16*)(ws + 6400000);         // [6.4M, 12.8M): 12.8M bf16 row-major
  bf16*   h2   = (bf16*)(ws + 12800000);        // [12.8M, 16M): interleaved [N][128]
  float*  as1  = ws + 16000000;                 // 200K
  float*  ad1  = ws + 16200000;                 // 200K
  float*  as2m = ws + 16400000;                 // 50K each
  float*  ad2m = ws + 16450000;
  float*  as2l = ws + 16500000;
  float*  ad2l = ws + 16550000;
  int*      offs  = (int*)(ws + 16600000);      // 50001
  int*      srcs  = (int*)(ws + 16650016);      // 850000
  unsigned* buck  = (unsigned*)(ws + 17500016); // 850000
  int*      bcnt  = (int*)(ws + 18350016);      // 256
  int*      bbase = (int*)(ws + 18350272);      // 257
  int*      bcur  = (int*)(ws + 18350544);      // 256
  unsigned* gm    = (unsigned*)(ws + 18350800); // 8
  bf16x8*   Bp1   = (bf16x8*)(ws + 18351040);   // 32768 bf16 (16B-aligned)
  bf16x8*   Bp2   = (bf16x8*)(ws + 18367424);   // 32768 bf16

  float* outmu = (float*)d_out;
  float* outls = (float*)d_out + 3200000;

  const int egrid4 = (Etot + 1023) / 1024;

  // ---- CSR build: two-phase LDS bucket sort ----
  hipMemsetAsync(bcnt, 0, 256 * sizeof(int), stream);
  hipMemsetAsync(gm, 0, 8 * sizeof(unsigned), stream);   // 0 < fenc(any finite float)
  bhist_k<<<egrid4, 256, 0, stream>>>(ei, E0, Etot, bcnt);
  bscan_k<<<1, 256, 0, stream>>>(bcnt, bbase, bcur, Etot);
  bscat_k<<<egrid4, 256, 0, stream>>>(ei, E0, Etot, bcur, buck);
  bcsr_k<<<NB, 256, 0, stream>>>(buck, bbase, offs, srcs, N);

  // ---- weight packing for MFMA ----
  cvt_w_k<<<32, 256, 0, stream>>>(W1, Wmu, Wls, Bp1, Bp2);

  // ---- layer 1: GATConv(128 -> 4x64, concat) + bias + ReLU ----
  gemm1_mfma<<<MT, 256, 0, stream>>>(x, Bp1, aS1, aD1, h1bf, as1, ad1, gm);
  gat_aggr1_k<<<(N + 1) / 2, 128, 0, stream>>>(offs, srcs, as1, ad1, gm, h1bf, b1, Ap2, N);

  // ---- layers mu & logstd: GATConv(256 -> 1x64) + bias ----
  gemm2_mfma<<<(MT + 3) / 4, 256, 0, stream>>>(Ap2, Bp2, aSmu, aDmu, aSls, aDls,
                                               h2, as2m, ad2m, as2l, ad2l, gm);
  gat_aggr2_k<<<(N + 1) / 2, 128, 0, stream>>>(offs, srcs, as2m, ad2m, as2l, ad2l,
                                               gm, h2, bmu, bls, outmu, outls, N);
}

// Round 17
// 271.158 us; speedup vs baseline: 1.5195x; 1.5195x over previous
//
#include <hip/hip_runtime.h>
#include <hip/hip_bf16.h>

#define NNODES 50000
#define MT 3125              // NNODES / 16 row-tiles
#define NB 196               // ceil(NNODES / 256) dst-buckets
typedef __hip_bfloat16 bf16;
typedef __attribute__((ext_vector_type(8))) short bf16x8;  // 8 bf16 (4 VGPRs)
typedef __attribute__((ext_vector_type(4))) float f32x4;   // 4 f32 acc

__device__ __forceinline__ void unpack2(unsigned w, float& lo, float& hi){
  lo = __uint_as_float(w << 16);
  hi = __uint_as_float(w & 0xffff0000u);
}
__device__ __forceinline__ short f2bf(float f){
  union { __hip_bfloat16 h; short s; } u; u.h = __float2bfloat16(f); return u.s;
}
__device__ __forceinline__ float lrelu(float v){ return v > 0.f ? v : 0.2f * v; }
__device__ __forceinline__ unsigned fenc(float f){
  unsigned u = __float_as_uint(f);
  return (u & 0x80000000u) ? ~u : (u | 0x80000000u);
}
__device__ __forceinline__ float fdec(unsigned u){
  unsigned b = (u & 0x80000000u) ? (u & 0x7fffffffu) : ~u;
  return __uint_as_float(b);
}
// contention-free global max: plain load filter, atomic only when needed.
// stale reads are harmless (value is monotone; atomicMax is the guard).
__device__ __forceinline__ void gmax_update(unsigned* p, float v){
  unsigned e = fenc(v);
  volatile unsigned* vp = (volatile unsigned*)p;
  if (e > *vp) atomicMax(p, e);
}

// ---------------- pack weights -> B-fragment bf16 ----------------
__global__ __launch_bounds__(256)
void cvt_w_k(const float* __restrict__ W1, const float* __restrict__ Wmu,
             const float* __restrict__ Wls, bf16x8* __restrict__ Bp1,
             bf16x8* __restrict__ Bp2){
  int t = blockIdx.x * 256 + threadIdx.x;
  if (t < 4096){
    int lane = t & 63, ct = (t >> 6) & 15, kt = t >> 10;
    int k0 = kt * 32 + (lane >> 4) * 8, col = ct * 16 + (lane & 15);
    bf16x8 o;
    #pragma unroll
    for (int j = 0; j < 8; j++) o[j] = f2bf(W1[(size_t)(k0 + j) * 256 + col]);
    Bp1[t] = o;
  } else if (t < 8192){
    int u = t - 4096;
    int lane = u & 63, ct = (u >> 6) & 7, kt = u >> 9;
    int k0 = kt * 32 + (lane >> 4) * 8, col = ct * 16 + (lane & 15);
    const float* W = (col < 64) ? Wmu : Wls;
    int cc = col & 63;
    bf16x8 o;
    #pragma unroll
    for (int j = 0; j < 8; j++) o[j] = f2bf(W[(size_t)(k0 + j) * 64 + cc]);
    Bp2[u] = o;
  }
}

// ------- MFMA GEMM 1 + fused alpha + fused per-head global max (filtered) -------
__global__ __launch_bounds__(256)
void gemm1_mfma(const float* __restrict__ x, const bf16x8* __restrict__ Bp,
                const float* __restrict__ aS, const float* __restrict__ aD,
                bf16* __restrict__ Y, float* __restrict__ as1, float* __restrict__ ad1,
                unsigned* __restrict__ gm){
  int rt = blockIdx.x;
  int w = threadIdx.x >> 6, lane = threadIdx.x & 63;
  const float* xr = x + (size_t)(rt * 16 + (lane & 15)) * 128 + (lane >> 4) * 8;
  f32x4 z = {0.f, 0.f, 0.f, 0.f};
  f32x4 acc[4] = {z, z, z, z};
  for (int kt = 0; kt < 4; kt++){
    float4 v0 = *(const float4*)(xr + kt * 32);
    float4 v1 = *(const float4*)(xr + kt * 32 + 4);
    bf16x8 a;
    a[0] = f2bf(v0.x); a[1] = f2bf(v0.y); a[2] = f2bf(v0.z); a[3] = f2bf(v0.w);
    a[4] = f2bf(v1.x); a[5] = f2bf(v1.y); a[6] = f2bf(v1.z); a[7] = f2bf(v1.w);
    #pragma unroll
    for (int c = 0; c < 4; c++){
      bf16x8 b = Bp[(size_t)(kt * 16 + w * 4 + c) * 64 + lane];
      acc[c] = __builtin_amdgcn_mfma_f32_16x16x32_bf16(a, b, acc[c], 0, 0, 0);
    }
  }
  int row0 = rt * 16 + (lane >> 4) * 4;
  #pragma unroll
  for (int c = 0; c < 4; c++){
    int col = w * 64 + c * 16 + (lane & 15);
    #pragma unroll
    for (int i = 0; i < 4; i++)
      Y[(size_t)(row0 + i) * 256 + col] = __float2bfloat16(acc[c][i]);
  }
  float aSv[4], aDv[4];
  #pragma unroll
  for (int c = 0; c < 4; c++){
    int col = c * 16 + (lane & 15);
    aSv[c] = aS[w * 64 + col];
    aDv[c] = aD[w * 64 + col];
  }
  float bm = -1e30f;
  #pragma unroll
  for (int i = 0; i < 4; i++){
    float s1 = 0.f, s2 = 0.f;
    #pragma unroll
    for (int c = 0; c < 4; c++){
      s1 = fmaf(acc[c][i], aSv[c], s1);
      s2 = fmaf(acc[c][i], aDv[c], s2);
    }
    #pragma unroll
    for (int o = 1; o < 16; o <<= 1){
      s1 += __shfl_xor(s1, o);
      s2 += __shfl_xor(s2, o);
    }
    bm = fmaxf(bm, s1);              // butterfly left s1 in all 16 lanes
    if ((lane & 15) == 0){
      int node = row0 + i;
      as1[node * 4 + w] = s1;
      ad1[node * 4 + w] = s2;
    }
  }
  bm = fmaxf(bm, __shfl_xor(bm, 16));
  bm = fmaxf(bm, __shfl_xor(bm, 32));
  if (lane == 0) gmax_update(&gm[w], bm);
}

// ------- MFMA GEMM 2: interleaved h2 + fused alphas + fused global max (filtered) -------
__global__ __launch_bounds__(256)
void gemm2_mfma(const bf16x8* __restrict__ Ap, const bf16x8* __restrict__ Bp,
                const float* __restrict__ aSmu, const float* __restrict__ aDmu,
                const float* __restrict__ aSls, const float* __restrict__ aDls,
                bf16* __restrict__ Y2,
                float* __restrict__ as2m, float* __restrict__ ad2m,
                float* __restrict__ as2l, float* __restrict__ ad2l,
                unsigned* __restrict__ gm){
  int w = threadIdx.x >> 6, lane = threadIdx.x & 63;
  int rt = blockIdx.x * 4 + w;
  if (rt >= MT) return;
  f32x4 z = {0.f, 0.f, 0.f, 0.f};
  f32x4 acc[8] = {z, z, z, z, z, z, z, z};   // 0-3 mu, 4-7 ls
  for (int kt = 0; kt < 8; kt++){
    bf16x8 a = Ap[(size_t)(rt * 8 + kt) * 64 + lane];
    #pragma unroll
    for (int c = 0; c < 8; c++){
      bf16x8 b = Bp[(size_t)(kt * 8 + c) * 64 + lane];
      acc[c] = __builtin_amdgcn_mfma_f32_16x16x32_bf16(a, b, acc[c], 0, 0, 0);
    }
  }
  int row0 = rt * 16 + (lane >> 4) * 4;
  #pragma unroll
  for (int c = 0; c < 4; c++){
    int col = c * 16 + (lane & 15);
    #pragma unroll
    for (int i = 0; i < 4; i++){
      Y2[(size_t)(row0 + i) * 128 + col]       = __float2bfloat16(acc[c][i]);
      Y2[(size_t)(row0 + i) * 128 + 64 + col]  = __float2bfloat16(acc[4 + c][i]);
    }
  }
  float aSm[4], aDm[4], aSl[4], aDl[4];
  #pragma unroll
  for (int c = 0; c < 4; c++){
    int col = c * 16 + (lane & 15);
    aSm[c] = aSmu[col]; aDm[c] = aDmu[col];
    aSl[c] = aSls[col]; aDl[c] = aDls[col];
  }
  float bm1 = -1e30f, bm3 = -1e30f;
  #pragma unroll
  for (int i = 0; i < 4; i++){
    float s1 = 0.f, s2 = 0.f, s3 = 0.f, s4 = 0.f;
    #pragma unroll
    for (int c = 0; c < 4; c++){
      s1 = fmaf(acc[c][i], aSm[c], s1);
      s2 = fmaf(acc[c][i], aDm[c], s2);
      s3 = fmaf(acc[4 + c][i], aSl[c], s3);
      s4 = fmaf(acc[4 + c][i], aDl[c], s4);
    }
    #pragma unroll
    for (int o = 1; o < 16; o <<= 1){
      s1 += __shfl_xor(s1, o);
      s2 += __shfl_xor(s2, o);
      s3 += __shfl_xor(s3, o);
      s4 += __shfl_xor(s4, o);
    }
    bm1 = fmaxf(bm1, s1);
    bm3 = fmaxf(bm3, s3);
    if ((lane & 15) == 0){
      int node = row0 + i;
      as2m[node] = s1; ad2m[node] = s2;
      as2l[node] = s3; ad2l[node] = s4;
    }
  }
  bm1 = fmaxf(bm1, __shfl_xor(bm1, 16));
  bm1 = fmaxf(bm1, __shfl_xor(bm1, 32));
  bm3 = fmaxf(bm3, __shfl_xor(bm3, 16));
  bm3 = fmaxf(bm3, __shfl_xor(bm3, 32));
  if (lane == 0){
    gmax_update(&gm[4], bm1);
    gmax_update(&gm[5], bm3);
  }
}

// ================ two-phase LDS bucket CSR build ================
__global__ __launch_bounds__(256)
void bhist_k(const int* __restrict__ ei, int E0, int Etot, int* __restrict__ bcnt){
  __shared__ int lh[NB];
  for (int i = threadIdx.x; i < NB; i += 256) lh[i] = 0;
  __syncthreads();
  int base = blockIdx.x * 1024 + threadIdx.x;
  #pragma unroll
  for (int q = 0; q < 4; q++){
    int e = base + q * 256;
    if (e < Etot){
      int d = (e < E0) ? ei[E0 + e] : e - E0;
      atomicAdd(&lh[d >> 8], 1);
    }
  }
  __syncthreads();
  for (int i = threadIdx.x; i < NB; i += 256)
    if (lh[i]) atomicAdd(&bcnt[i], lh[i]);
}

__global__ __launch_bounds__(256)
void bscan_k(const int* __restrict__ bcnt, int* __restrict__ bbase,
             int* __restrict__ bcur, int total){
  __shared__ int buf[256];
  int t = threadIdx.x;
  int v = (t < NB) ? bcnt[t] : 0;
  buf[t] = v; __syncthreads();
  int acc = v;
  for (int off = 1; off < 256; off <<= 1){
    int x = (t >= off) ? buf[t - off] : 0;
    __syncthreads();
    acc += x; buf[t] = acc; __syncthreads();
  }
  if (t < NB){ int ex = acc - v; bbase[t] = ex; bcur[t] = ex; }
  if (t == 0) bbase[NB] = total;
}

__global__ __launch_bounds__(256)
void bscat_k(const int* __restrict__ ei, int E0, int Etot,
             int* __restrict__ bcur, unsigned* __restrict__ buck){
  __shared__ int lh[NB];
  __shared__ int lbase[NB];
  for (int i = threadIdx.x; i < NB; i += 256) lh[i] = 0;
  __syncthreads();
  int base = blockIdx.x * 1024 + threadIdx.x;
  int sA[4], dA[4], rA[4];
  #pragma unroll
  for (int q = 0; q < 4; q++){
    int e = base + q * 256;
    sA[q] = -1;
    if (e < Etot){
      int s, d;
      if (e < E0){ s = ei[e]; d = ei[E0 + e]; } else { s = d = e - E0; }
      sA[q] = s; dA[q] = d;
      rA[q] = atomicAdd(&lh[d >> 8], 1);
    }
  }
  __syncthreads();
  for (int i = threadIdx.x; i < NB; i += 256)
    lbase[i] = lh[i] ? atomicAdd(&bcur[i], lh[i]) : 0;
  __syncthreads();
  #pragma unroll
  for (int q = 0; q < 4; q++){
    if (sA[q] >= 0){
      int bk = dA[q] >> 8;
      buck[lbase[bk] + rA[q]] = ((unsigned)(dA[q] & 255) << 16) | (unsigned)sA[q];
    }
  }
}

__global__ __launch_bounds__(256)
void bcsr_k(const unsigned* __restrict__ buck, const int* __restrict__ bbase,
            int* __restrict__ offs, int* __restrict__ srcs, int n){
  int b = blockIdx.x;
  int lo = bbase[b], hi = bbase[b + 1];
  __shared__ int eh[256];
  __shared__ int buf[256];
  int t = threadIdx.x;
  eh[t] = 0;
  __syncthreads();
  for (int j = lo + t; j < hi; j += 256)
    atomicAdd(&eh[(buck[j] >> 16) & 255], 1);
  __syncthreads();
  int v = eh[t];
  buf[t] = v; __syncthreads();
  int acc = v;
  for (int off = 1; off < 256; off <<= 1){
    int x = (t >= off) ? buf[t - off] : 0;
    __syncthreads();
    acc += x; buf[t] = acc; __syncthreads();
  }
  int loff = acc - v;   // exclusive within bucket
  int node = b * 256 + t;
  if (node < n) offs[node] = lo + loff;
  if (b == NB - 1 && t == 0) offs[n] = bbase[NB];
  __syncthreads();
  eh[t] = loff;        // reuse as cursors
  __syncthreads();
  for (int j = lo + t; j < hi; j += 256){
    unsigned val = buck[j];
    int dlo = (val >> 16) & 255;
    int rank = atomicAdd(&eh[dlo], 1);
    srcs[lo + rank] = (int)(val & 0xffffu);
  }
}

// ------- aggregation layer 1: 2 nodes/block, GLOBAL max bound (no pass A) -------
// pass2: slot = lane>>5 (2), head = (lane>>3)&3, oct = lane&7  (R15 form, VGPR 20)
__global__ __launch_bounds__(128)
void gat_aggr1_k(const int* __restrict__ offs, const int* __restrict__ srcs,
                 const float* __restrict__ as, const float* __restrict__ ad,
                 const unsigned* __restrict__ gm,
                 const bf16* __restrict__ h, const float* __restrict__ b,
                 bf16x8* __restrict__ Ap2, int n){
  int node = blockIdx.x * 2 + (threadIdx.x >> 6);
  if (node >= n) return;
  int lane = threadIdx.x & 63;
  int beg = offs[node], end = offs[node + 1];
  int hP = (lane >> 3) & 3, oct = lane & 7, slot = lane >> 5;
  float advP = ad[node * 4 + hP];
  float mP = lrelu(fdec(gm[hP]) + advP);   // upper bound on every edge logit
  float s = 0.f;
  float acc[8];
  #pragma unroll
  for (int i = 0; i < 8; i++) acc[i] = 0.f;
  #pragma unroll 8
  for (int j0 = beg; j0 < end; j0 += 2){
    int j = j0 + slot;
    if (j < end){
      int si = srcs[j];
      float e = lrelu(as[si * 4 + hP] + advP);
      float p = __expf(e - mP);
      s += p;
      uint4 dw = *(const uint4*)(h + (size_t)si * 256 + hP * 64 + oct * 8);
      float lo, hi;
      unpack2(dw.x, lo, hi); acc[0] = fmaf(lo, p, acc[0]); acc[1] = fmaf(hi, p, acc[1]);
      unpack2(dw.y, lo, hi); acc[2] = fmaf(lo, p, acc[2]); acc[3] = fmaf(hi, p, acc[3]);
      unpack2(dw.z, lo, hi); acc[4] = fmaf(lo, p, acc[4]); acc[5] = fmaf(hi, p, acc[5]);
      unpack2(dw.w, lo, hi); acc[6] = fmaf(lo, p, acc[6]); acc[7] = fmaf(hi, p, acc[7]);
    }
  }
  s += __shfl_xor(s, 32);
  #pragma unroll
  for (int i = 0; i < 8; i++) acc[i] += __shfl_xor(acc[i], 32);
  if (lane < 32){
    float inv = 1.f / (s + 1e-16f);
    bf16x8 o;
    #pragma unroll
    for (int i = 0; i < 8; i++){
      float vv = acc[i] * inv + b[lane * 8 + i];
      o[i] = f2bf(vv > 0.f ? vv : 0.f);
    }
    int kt = lane >> 2, g = lane & 3;
    int rt = node >> 4, r = node & 15;
    Ap2[(size_t)(rt * 8 + kt) * 64 + g * 16 + r] = o;
  }
}

// ------- aggregation mu & logstd: interleaved h2, GLOBAL max, guard-free bulk -------
// pass2: slot = lane>>4 (4), branch = (lane>>3)&1, oct = lane&7
__global__ __launch_bounds__(128)
void gat_aggr2_k(const int* __restrict__ offs, const int* __restrict__ srcs,
                 const float* __restrict__ as2m, const float* __restrict__ ad2m,
                 const float* __restrict__ as2l, const float* __restrict__ ad2l,
                 const unsigned* __restrict__ gm,
                 const bf16* __restrict__ h2,
                 const float* __restrict__ bmu, const float* __restrict__ bls,
                 float* __restrict__ outmu, float* __restrict__ outls, int n){
  int node = blockIdx.x * 2 + (threadIdx.x >> 6);
  if (node >= n) return;
  int lane = threadIdx.x & 63;
  int beg = offs[node], end = offs[node + 1];
  int deg = end - beg;
  int br = (lane >> 3) & 1, oct = lane & 7, slot = lane >> 4;
  const float* asP = br ? as2l : as2m;
  float advP = (br ? ad2l : ad2m)[node];
  float mP = lrelu(fdec(gm[4 + br]) + advP);
  float s = 0.f;
  float acc[8];
  #pragma unroll
  for (int i = 0; i < 8; i++) acc[i] = 0.f;
  int bulk = beg + (deg & ~3);
  #pragma unroll 4
  for (int j0 = beg; j0 < bulk; j0 += 4){
    int si = srcs[j0 + slot];
    float e = lrelu(asP[si] + advP);
    float p = __expf(e - mP);
    s += p;
    uint4 dw = *(const uint4*)(h2 + (size_t)si * 128 + br * 64 + oct * 8);
    float lo, hi;
    unpack2(dw.x, lo, hi); acc[0] = fmaf(lo, p, acc[0]); acc[1] = fmaf(hi, p, acc[1]);
    unpack2(dw.y, lo, hi); acc[2] = fmaf(lo, p, acc[2]); acc[3] = fmaf(hi, p, acc[3]);
    unpack2(dw.z, lo, hi); acc[4] = fmaf(lo, p, acc[4]); acc[5] = fmaf(hi, p, acc[5]);
    unpack2(dw.w, lo, hi); acc[6] = fmaf(lo, p, acc[6]); acc[7] = fmaf(hi, p, acc[7]);
  }
  {
    int j = bulk + slot;
    if (j < end){
      int si = srcs[j];
      float e = lrelu(asP[si] + advP);
      float p = __expf(e - mP);
      s += p;
      uint4 dw = *(const uint4*)(h2 + (size_t)si * 128 + br * 64 + oct * 8);
      float lo, hi;
      unpack2(dw.x, lo, hi); acc[0] = fmaf(lo, p, acc[0]); acc[1] = fmaf(hi, p, acc[1]);
      unpack2(dw.y, lo, hi); acc[2] = fmaf(lo, p, acc[2]); acc[3] = fmaf(hi, p, acc[3]);
      unpack2(dw.z, lo, hi); acc[4] = fmaf(lo, p, acc[4]); acc[5] = fmaf(hi, p, acc[5]);
      unpack2(dw.w, lo, hi); acc[6] = fmaf(lo, p, acc[6]); acc[7] = fmaf(hi, p, acc[7]);
    }
  }
  #pragma unroll
  for (int off = 16; off <= 32; off <<= 1){
    s += __shfl_xor(s, off);
    #pragma unroll
    for (int i = 0; i < 8; i++) acc[i] += __shfl_xor(acc[i], off);
  }
  if (lane < 16){
    float inv = 1.f / (s + 1e-16f);
    const float* bb = (lane >= 8) ? bls : bmu;
    float* out = (lane >= 8) ? outls : outmu;
    float v[8];
    #pragma unroll
    for (int i = 0; i < 8; i++) v[i] = acc[i] * inv + bb[oct * 8 + i];
    float* op = out + (size_t)node * 64 + oct * 8;
    *(float4*)op       = make_float4(v[0], v[1], v[2], v[3]);
    *(float4*)(op + 4) = make_float4(v[4], v[5], v[6], v[7]);
  }
}

extern "C" void kernel_launch(void* const* d_in, const int* in_sizes, int n_in,
                              void* d_out, int out_size, void* d_ws, size_t ws_size,
                              hipStream_t stream){
  const float* x    = (const float*)d_in[0];
  const int*   ei   = (const int*)d_in[1];
  const float* W1   = (const float*)d_in[2];
  const float* aS1  = (const float*)d_in[3];
  const float* aD1  = (const float*)d_in[4];
  const float* b1   = (const float*)d_in[5];
  const float* Wmu  = (const float*)d_in[6];
  const float* aSmu = (const float*)d_in[7];
  const float* aDmu = (const float*)d_in[8];
  const float* bmu  = (const float*)d_in[9];
  const float* Wls  = (const float*)d_in[10];
  const float* aSls = (const float*)d_in[11];
  const float* aDls = (const float*)d_in[12];
  const float* bls  = (const float*)d_in[13];

  const int N    = NNODES;
  const int E0   = in_sizes[1] / 2;
  const int Etot = E0 + N;

  // ---- workspace layout (float-unit offsets; bf16x8 arrays 16B-aligned) ----
  float* ws = (float*)d_ws;
  bf16x8* Ap2  = (bf16x8*)(ws);                 // [0, 6.4M): layer-1 out, packed A-frag
  bf16*   h1bf = (bf16*)(ws + 6400000);         // [6.4M, 12.8M): 12.8M bf16 row-major
  bf16*   h2   = (bf16*)(ws + 12800000);        // [12.8M, 16M): interleaved [N][128]
  float*  as1  = ws + 16000000;                 // 200K
  float*  ad1  = ws + 16200000;                 // 200K
  float*  as2m = ws + 16400000;                 // 50K each
  float*  ad2m = ws + 16450000;
  float*  as2l = ws + 16500000;
  float*  ad2l = ws + 16550000;
  int*      offs  = (int*)(ws + 16600000);      // 50001
  int*      srcs  = (int*)(ws + 16650016);      // 850000
  unsigned* buck  = (unsigned*)(ws + 17500016); // 850000
  int*      bcnt  = (int*)(ws + 18350016);      // 256
  int*      bbase = (int*)(ws + 18350272);      // 257
  int*      bcur  = (int*)(ws + 18350544);      // 256
  unsigned* gm    = (unsigned*)(ws + 18350800); // 8
  bf16x8*   Bp1   = (bf16x8*)(ws + 18351040);   // 32768 bf16 (16B-aligned)
  bf16x8*   Bp2   = (bf16x8*)(ws + 18367424);   // 32768 bf16

  float* outmu = (float*)d_out;
  float* outls = (float*)d_out + 3200000;

  const int egrid4 = (Etot + 1023) / 1024;

  // ---- CSR build: two-phase LDS bucket sort ----
  hipMemsetAsync(bcnt, 0, 256 * sizeof(int), stream);
  hipMemsetAsync(gm, 0, 8 * sizeof(unsigned), stream);   // 0 < fenc(any finite float)
  bhist_k<<<egrid4, 256, 0, stream>>>(ei, E0, Etot, bcnt);
  bscan_k<<<1, 256, 0, stream>>>(bcnt, bbase, bcur, Etot);
  bscat_k<<<egrid4, 256, 0, stream>>>(ei, E0, Etot, bcur, buck);
  bcsr_k<<<NB, 256, 0, stream>>>(buck, bbase, offs, srcs, N);

  // ---- weight packing for MFMA ----
  cvt_w_k<<<32, 256, 0, stream>>>(W1, Wmu, Wls, Bp1, Bp2);

  // ---- layer 1: GATConv(128 -> 4x64, concat) + bias + ReLU ----
  gemm1_mfma<<<MT, 256, 0, stream>>>(x, Bp1, aS1, aD1, h1bf, as1, ad1, gm);
  gat_aggr1_k<<<(N + 1) / 2, 128, 0, stream>>>(offs, srcs, as1, ad1, gm, h1bf, b1, Ap2, N);

  // ---- layers mu & logstd: GATConv(256 -> 1x64) + bias ----
  gemm2_mfma<<<(MT + 3) / 4, 256, 0, stream>>>(Ap2, Bp2, aSmu, aDmu, aSls, aDls,
                                               h2, as2m, ad2m, as2l, ad2l, gm);
  gat_aggr2_k<<<(N + 1) / 2, 128, 0, stream>>>(offs, srcs, as2m, ad2m, as2l, ad2l,
                                               gm, h2, bmu, bls, outmu, outls, N);
}

// Round 18
// 230.885 us; speedup vs baseline: 1.7846x; 1.1744x over previous
//
#include <hip/hip_runtime.h>
#include <hip/hip_bf16.h>

#define NNODES 50000
#define MT 3125              // NNODES / 16 row-tiles
#define NB 196               // ceil(NNODES / 256) dst-buckets
typedef __hip_bfloat16 bf16;
typedef __attribute__((ext_vector_type(8))) short bf16x8;  // 8 bf16 (4 VGPRs)
typedef __attribute__((ext_vector_type(4))) float f32x4;   // 4 f32 acc

__device__ __forceinline__ void unpack2(unsigned w, float& lo, float& hi){
  lo = __uint_as_float(w << 16);
  hi = __uint_as_float(w & 0xffff0000u);
}
__device__ __forceinline__ short f2bf(float f){
  union { __hip_bfloat16 h; short s; } u; u.h = __float2bfloat16(f); return u.s;
}
__device__ __forceinline__ float lrelu(float v){ return v > 0.f ? v : 0.2f * v; }

// ---------------- pack weights -> B-fragment bf16 ----------------
__global__ __launch_bounds__(256)
void cvt_w_k(const float* __restrict__ W1, const float* __restrict__ Wmu,
             const float* __restrict__ Wls, bf16x8* __restrict__ Bp1,
             bf16x8* __restrict__ Bp2){
  int t = blockIdx.x * 256 + threadIdx.x;
  if (t < 4096){
    int lane = t & 63, ct = (t >> 6) & 15, kt = t >> 10;
    int k0 = kt * 32 + (lane >> 4) * 8, col = ct * 16 + (lane & 15);
    bf16x8 o;
    #pragma unroll
    for (int j = 0; j < 8; j++) o[j] = f2bf(W1[(size_t)(k0 + j) * 256 + col]);
    Bp1[t] = o;
  } else if (t < 8192){
    int u = t - 4096;
    int lane = u & 63, ct = (u >> 6) & 7, kt = u >> 9;
    int k0 = kt * 32 + (lane >> 4) * 8, col = ct * 16 + (lane & 15);
    const float* W = (col < 64) ? Wmu : Wls;
    int cc = col & 63;
    bf16x8 o;
    #pragma unroll
    for (int j = 0; j < 8; j++) o[j] = f2bf(W[(size_t)(k0 + j) * 64 + cc]);
    Bp2[u] = o;
  }
}

// ------- MFMA GEMM 1 (reads f32 x directly) + fused alpha -------
__global__ __launch_bounds__(256)
void gemm1_mfma(const float* __restrict__ x, const bf16x8* __restrict__ Bp,
                const float* __restrict__ aS, const float* __restrict__ aD,
                bf16* __restrict__ Y, float* __restrict__ as1, float* __restrict__ ad1){
  int rt = blockIdx.x;
  int w = threadIdx.x >> 6, lane = threadIdx.x & 63;
  const float* xr = x + (size_t)(rt * 16 + (lane & 15)) * 128 + (lane >> 4) * 8;
  f32x4 z = {0.f, 0.f, 0.f, 0.f};
  f32x4 acc[4] = {z, z, z, z};
  for (int kt = 0; kt < 4; kt++){
    float4 v0 = *(const float4*)(xr + kt * 32);
    float4 v1 = *(const float4*)(xr + kt * 32 + 4);
    bf16x8 a;
    a[0] = f2bf(v0.x); a[1] = f2bf(v0.y); a[2] = f2bf(v0.z); a[3] = f2bf(v0.w);
    a[4] = f2bf(v1.x); a[5] = f2bf(v1.y); a[6] = f2bf(v1.z); a[7] = f2bf(v1.w);
    #pragma unroll
    for (int c = 0; c < 4; c++){
      bf16x8 b = Bp[(size_t)(kt * 16 + w * 4 + c) * 64 + lane];
      acc[c] = __builtin_amdgcn_mfma_f32_16x16x32_bf16(a, b, acc[c], 0, 0, 0);
    }
  }
  int row0 = rt * 16 + (lane >> 4) * 4;
  #pragma unroll
  for (int c = 0; c < 4; c++){
    int col = w * 64 + c * 16 + (lane & 15);
    #pragma unroll
    for (int i = 0; i < 4; i++)
      Y[(size_t)(row0 + i) * 256 + col] = __float2bfloat16(acc[c][i]);
  }
  float aSv[4], aDv[4];
  #pragma unroll
  for (int c = 0; c < 4; c++){
    int col = c * 16 + (lane & 15);
    aSv[c] = aS[w * 64 + col];
    aDv[c] = aD[w * 64 + col];
  }
  #pragma unroll
  for (int i = 0; i < 4; i++){
    float s1 = 0.f, s2 = 0.f;
    #pragma unroll
    for (int c = 0; c < 4; c++){
      s1 = fmaf(acc[c][i], aSv[c], s1);
      s2 = fmaf(acc[c][i], aDv[c], s2);
    }
    #pragma unroll
    for (int o = 1; o < 16; o <<= 1){
      s1 += __shfl_xor(s1, o);
      s2 += __shfl_xor(s2, o);
    }
    if ((lane & 15) == 0){
      int node = row0 + i;
      as1[node * 4 + w] = s1;
      ad1[node * 4 + w] = s2;
    }
  }
}

// ------- MFMA GEMM 2: one wave = one row-tile, BOTH branches + fused alphas -------
// writes interleaved h2[node][128]: cols 0-63 mu, 64-127 ls
__global__ __launch_bounds__(256)
void gemm2_mfma(const bf16x8* __restrict__ Ap, const bf16x8* __restrict__ Bp,
                const float* __restrict__ aSmu, const float* __restrict__ aDmu,
                const float* __restrict__ aSls, const float* __restrict__ aDls,
                bf16* __restrict__ Y2,
                float* __restrict__ as2m, float* __restrict__ ad2m,
                float* __restrict__ as2l, float* __restrict__ ad2l){
  int w = threadIdx.x >> 6, lane = threadIdx.x & 63;
  int rt = blockIdx.x * 4 + w;
  if (rt >= MT) return;
  f32x4 z = {0.f, 0.f, 0.f, 0.f};
  f32x4 acc[8] = {z, z, z, z, z, z, z, z};   // 0-3 mu, 4-7 ls
  for (int kt = 0; kt < 8; kt++){
    bf16x8 a = Ap[(size_t)(rt * 8 + kt) * 64 + lane];
    #pragma unroll
    for (int c = 0; c < 8; c++){
      bf16x8 b = Bp[(size_t)(kt * 8 + c) * 64 + lane];
      acc[c] = __builtin_amdgcn_mfma_f32_16x16x32_bf16(a, b, acc[c], 0, 0, 0);
    }
  }
  int row0 = rt * 16 + (lane >> 4) * 4;
  #pragma unroll
  for (int c = 0; c < 4; c++){
    int col = c * 16 + (lane & 15);
    #pragma unroll
    for (int i = 0; i < 4; i++){
      Y2[(size_t)(row0 + i) * 128 + col]       = __float2bfloat16(acc[c][i]);
      Y2[(size_t)(row0 + i) * 128 + 64 + col]  = __float2bfloat16(acc[4 + c][i]);
    }
  }
  float aSm[4], aDm[4], aSl[4], aDl[4];
  #pragma unroll
  for (int c = 0; c < 4; c++){
    int col = c * 16 + (lane & 15);
    aSm[c] = aSmu[col]; aDm[c] = aDmu[col];
    aSl[c] = aSls[col]; aDl[c] = aDls[col];
  }
  #pragma unroll
  for (int i = 0; i < 4; i++){
    float s1 = 0.f, s2 = 0.f, s3 = 0.f, s4 = 0.f;
    #pragma unroll
    for (int c = 0; c < 4; c++){
      s1 = fmaf(acc[c][i], aSm[c], s1);
      s2 = fmaf(acc[c][i], aDm[c], s2);
      s3 = fmaf(acc[4 + c][i], aSl[c], s3);
      s4 = fmaf(acc[4 + c][i], aDl[c], s4);
    }
    #pragma unroll
    for (int o = 1; o < 16; o <<= 1){
      s1 += __shfl_xor(s1, o);
      s2 += __shfl_xor(s2, o);
      s3 += __shfl_xor(s3, o);
      s4 += __shfl_xor(s4, o);
    }
    if ((lane & 15) == 0){
      int node = row0 + i;
      as2m[node] = s1; ad2m[node] = s2;
      as2l[node] = s3; ad2l[node] = s4;
    }
  }
}

// ================ two-phase LDS bucket CSR build ================
__global__ __launch_bounds__(256)
void bhist_k(const int* __restrict__ ei, int E0, int Etot, int* __restrict__ bcnt){
  __shared__ int lh[NB];
  for (int i = threadIdx.x; i < NB; i += 256) lh[i] = 0;
  __syncthreads();
  int base = blockIdx.x * 1024 + threadIdx.x;
  #pragma unroll
  for (int q = 0; q < 4; q++){
    int e = base + q * 256;
    if (e < Etot){
      int d = (e < E0) ? ei[E0 + e] : e - E0;
      atomicAdd(&lh[d >> 8], 1);
    }
  }
  __syncthreads();
  for (int i = threadIdx.x; i < NB; i += 256)
    if (lh[i]) atomicAdd(&bcnt[i], lh[i]);
}

__global__ __launch_bounds__(256)
void bscan_k(const int* __restrict__ bcnt, int* __restrict__ bbase,
             int* __restrict__ bcur, int total){
  __shared__ int buf[256];
  int t = threadIdx.x;
  int v = (t < NB) ? bcnt[t] : 0;
  buf[t] = v; __syncthreads();
  int acc = v;
  for (int off = 1; off < 256; off <<= 1){
    int x = (t >= off) ? buf[t - off] : 0;
    __syncthreads();
    acc += x; buf[t] = acc; __syncthreads();
  }
  if (t < NB){ int ex = acc - v; bbase[t] = ex; bcur[t] = ex; }
  if (t == 0) bbase[NB] = total;
}

__global__ __launch_bounds__(256)
void bscat_k(const int* __restrict__ ei, int E0, int Etot,
             int* __restrict__ bcur, unsigned* __restrict__ buck){
  __shared__ int lh[NB];
  __shared__ int lbase[NB];
  for (int i = threadIdx.x; i < NB; i += 256) lh[i] = 0;
  __syncthreads();
  int base = blockIdx.x * 1024 + threadIdx.x;
  int sA[4], dA[4], rA[4];
  #pragma unroll
  for (int q = 0; q < 4; q++){
    int e = base + q * 256;
    sA[q] = -1;
    if (e < Etot){
      int s, d;
      if (e < E0){ s = ei[e]; d = ei[E0 + e]; } else { s = d = e - E0; }
      sA[q] = s; dA[q] = d;
      rA[q] = atomicAdd(&lh[d >> 8], 1);
    }
  }
  __syncthreads();
  for (int i = threadIdx.x; i < NB; i += 256)
    lbase[i] = lh[i] ? atomicAdd(&bcur[i], lh[i]) : 0;
  __syncthreads();
  #pragma unroll
  for (int q = 0; q < 4; q++){
    if (sA[q] >= 0){
      int bk = dA[q] >> 8;
      buck[lbase[bk] + rA[q]] = ((unsigned)(dA[q] & 255) << 16) | (unsigned)sA[q];
    }
  }
}

__global__ __launch_bounds__(256)
void bcsr_k(const unsigned* __restrict__ buck, const int* __restrict__ bbase,
            int* __restrict__ offs, int* __restrict__ srcs, int n){
  int b = blockIdx.x;
  int lo = bbase[b], hi = bbase[b + 1];
  __shared__ int eh[256];
  __shared__ int buf[256];
  int t = threadIdx.x;
  eh[t] = 0;
  __syncthreads();
  for (int j = lo + t; j < hi; j += 256)
    atomicAdd(&eh[(buck[j] >> 16) & 255], 1);
  __syncthreads();
  int v = eh[t];
  buf[t] = v; __syncthreads();
  int acc = v;
  for (int off = 1; off < 256; off <<= 1){
    int x = (t >= off) ? buf[t - off] : 0;
    __syncthreads();
    acc += x; buf[t] = acc; __syncthreads();
  }
  int loff = acc - v;   // exclusive within bucket
  int node = b * 256 + t;
  if (node < n) offs[node] = lo + loff;
  if (b == NB - 1 && t == 0) offs[n] = bbase[NB];
  __syncthreads();
  eh[t] = loff;        // reuse as cursors
  __syncthreads();
  for (int j = lo + t; j < hi; j += 256){
    unsigned val = buck[j];
    int dlo = (val >> 16) & 255;
    int rank = atomicAdd(&eh[dlo], 1);
    srcs[lo + rank] = (int)(val & 0xffffu);
  }
}

// ------- aggregation layer 1: 2 nodes/block, pass-A max, predicated pass 2 -------
__global__ __launch_bounds__(128)
void gat_aggr1_k(const int* __restrict__ offs, const int* __restrict__ srcs,
                 const float* __restrict__ as, const float* __restrict__ ad,
                 const bf16* __restrict__ h, const float* __restrict__ b,
                 bf16x8* __restrict__ Ap2, int n){
  int node = blockIdx.x * 2 + (threadIdx.x >> 6);
  if (node >= n) return;
  int lane = threadIdx.x & 63;
  int beg = offs[node], end = offs[node + 1];
  int hA = lane >> 4, iA = lane & 15;
  float advA = ad[node * 4 + hA];
  float m = -1e30f;
  for (int j = beg + iA; j < end; j += 16)
    m = fmaxf(m, lrelu(as[srcs[j] * 4 + hA] + advA));
  #pragma unroll
  for (int o = 1; o < 16; o <<= 1) m = fmaxf(m, __shfl_xor(m, o));
  int hP = (lane >> 3) & 3, oct = lane & 7, slot = lane >> 5;
  float mP   = __shfl(m, hP * 16);
  float advP = __shfl(advA, hP * 16);
  float s = 0.f;
  float acc[8];
  #pragma unroll
  for (int i = 0; i < 8; i++) acc[i] = 0.f;
  #pragma unroll 8
  for (int j0 = beg; j0 < end; j0 += 2){
    int j = j0 + slot;
    if (j < end){
      int si = srcs[j];
      float e = lrelu(as[si * 4 + hP] + advP);
      float p = __expf(e - mP);
      s += p;
      uint4 dw = *(const uint4*)(h + (size_t)si * 256 + hP * 64 + oct * 8);
      float lo, hi;
      unpack2(dw.x, lo, hi); acc[0] = fmaf(lo, p, acc[0]); acc[1] = fmaf(hi, p, acc[1]);
      unpack2(dw.y, lo, hi); acc[2] = fmaf(lo, p, acc[2]); acc[3] = fmaf(hi, p, acc[3]);
      unpack2(dw.z, lo, hi); acc[4] = fmaf(lo, p, acc[4]); acc[5] = fmaf(hi, p, acc[5]);
      unpack2(dw.w, lo, hi); acc[6] = fmaf(lo, p, acc[6]); acc[7] = fmaf(hi, p, acc[7]);
    }
  }
  s += __shfl_xor(s, 32);
  #pragma unroll
  for (int i = 0; i < 8; i++) acc[i] += __shfl_xor(acc[i], 32);
  if (lane < 32){
    float inv = 1.f / (s + 1e-16f);
    bf16x8 o;
    #pragma unroll
    for (int i = 0; i < 8; i++){
      float vv = acc[i] * inv + b[lane * 8 + i];
      o[i] = f2bf(vv > 0.f ? vv : 0.f);
    }
    int kt = lane >> 2, g = lane & 3;
    int rt = node >> 4, r = node & 15;
    Ap2[(size_t)(rt * 8 + kt) * 64 + g * 16 + r] = o;
  }
}

// ------- aggregation mu & logstd: interleaved h2, pass-A max, predicated unroll-8 -------
__global__ __launch_bounds__(128)
void gat_aggr2_k(const int* __restrict__ offs, const int* __restrict__ srcs,
                 const float* __restrict__ as2m, const float* __restrict__ ad2m,
                 const float* __restrict__ as2l, const float* __restrict__ ad2l,
                 const bf16* __restrict__ h2,
                 const float* __restrict__ bmu, const float* __restrict__ bls,
                 float* __restrict__ outmu, float* __restrict__ outls, int n){
  int node = blockIdx.x * 2 + (threadIdx.x >> 6);
  if (node >= n) return;
  int lane = threadIdx.x & 63;
  int beg = offs[node], end = offs[node + 1];
  const float* asA = (lane >= 32) ? as2l : as2m;
  float advA = ((lane >= 32) ? ad2l : ad2m)[node];
  int iA = lane & 31;
  float m = -1e30f;
  for (int j = beg + iA; j < end; j += 32)
    m = fmaxf(m, lrelu(asA[srcs[j]] + advA));
  #pragma unroll
  for (int o = 1; o < 32; o <<= 1) m = fmaxf(m, __shfl_xor(m, o));
  int br = (lane >> 3) & 1, oct = lane & 7, slot = lane >> 4;
  float mP   = __shfl(m, br * 32);
  float advP = __shfl(advA, br * 32);
  const float* asP = br ? as2l : as2m;
  float s = 0.f;
  float acc[8];
  #pragma unroll
  for (int i = 0; i < 8; i++) acc[i] = 0.f;
  #pragma unroll 8
  for (int j0 = beg; j0 < end; j0 += 4){
    int j = j0 + slot;
    if (j < end){
      int si = srcs[j];
      float e = lrelu(asP[si] + advP);
      float p = __expf(e - mP);
      s += p;
      uint4 dw = *(const uint4*)(h2 + (size_t)si * 128 + br * 64 + oct * 8);
      float lo, hi;
      unpack2(dw.x, lo, hi); acc[0] = fmaf(lo, p, acc[0]); acc[1] = fmaf(hi, p, acc[1]);
      unpack2(dw.y, lo, hi); acc[2] = fmaf(lo, p, acc[2]); acc[3] = fmaf(hi, p, acc[3]);
      unpack2(dw.z, lo, hi); acc[4] = fmaf(lo, p, acc[4]); acc[5] = fmaf(hi, p, acc[5]);
      unpack2(dw.w, lo, hi); acc[6] = fmaf(lo, p, acc[6]); acc[7] = fmaf(hi, p, acc[7]);
    }
  }
  #pragma unroll
  for (int off = 16; off <= 32; off <<= 1){
    s += __shfl_xor(s, off);
    #pragma unroll
    for (int i = 0; i < 8; i++) acc[i] += __shfl_xor(acc[i], off);
  }
  if (lane < 16){
    float inv = 1.f / (s + 1e-16f);
    const float* bb = (lane >= 8) ? bls : bmu;
    float* out = (lane >= 8) ? outls : outmu;
    float v[8];
    #pragma unroll
    for (int i = 0; i < 8; i++) v[i] = acc[i] * inv + bb[oct * 8 + i];
    float* op = out + (size_t)node * 64 + oct * 8;
    *(float4*)op       = make_float4(v[0], v[1], v[2], v[3]);
    *(float4*)(op + 4) = make_float4(v[4], v[5], v[6], v[7]);
  }
}

extern "C" void kernel_launch(void* const* d_in, const int* in_sizes, int n_in,
                              void* d_out, int out_size, void* d_ws, size_t ws_size,
                              hipStream_t stream){
  const float* x    = (const float*)d_in[0];
  const int*   ei   = (const int*)d_in[1];
  const float* W1   = (const float*)d_in[2];
  const float* aS1  = (const float*)d_in[3];
  const float* aD1  = (const float*)d_in[4];
  const float* b1   = (const float*)d_in[5];
  const float* Wmu  = (const float*)d_in[6];
  const float* aSmu = (const float*)d_in[7];
  const float* aDmu = (const float*)d_in[8];
  const float* bmu  = (const float*)d_in[9];
  const float* Wls  = (const float*)d_in[10];
  const float* aSls = (const float*)d_in[11];
  const float* aDls = (const float*)d_in[12];
  const float* bls  = (const float*)d_in[13];

  const int N    = NNODES;
  const int E0   = in_sizes[1] / 2;
  const int Etot = E0 + N;

  // ---- workspace layout (float-unit offsets; bf16x8 arrays 16B-aligned) ----
  float* ws = (float*)d_ws;
  bf16x8* Ap2  = (bf16x8*)(ws);                 // [0, 6.4M): layer-1 out, packed A-frag
  bf16*   h1bf = (bf16*)(ws + 6400000);         // [6.4M, 12.8M): 12.8M bf16 row-major
  bf16*   h2   = (bf16*)(ws + 12800000);        // [12.8M, 16M): interleaved [N][128]
  float*  as1  = ws + 16000000;                 // 200K
  float*  ad1  = ws + 16200000;                 // 200K
  float*  as2m = ws + 16400000;                 // 50K each
  float*  ad2m = ws + 16450000;
  float*  as2l = ws + 16500000;
  float*  ad2l = ws + 16550000;
  int*      offs  = (int*)(ws + 16600000);      // 50001
  int*      srcs  = (int*)(ws + 16650016);      // 850000
  unsigned* buck  = (unsigned*)(ws + 17500016); // 850000
  int*      bcnt  = (int*)(ws + 18350016);      // 256
  int*      bbase = (int*)(ws + 18350272);      // 257
  int*      bcur  = (int*)(ws + 18350544);      // 256
  bf16x8*   Bp1   = (bf16x8*)(ws + 18351040);   // 32768 bf16 (16B-aligned)
  bf16x8*   Bp2   = (bf16x8*)(ws + 18367424);   // 32768 bf16

  float* outmu = (float*)d_out;
  float* outls = (float*)d_out + 3200000;

  const int egrid4 = (Etot + 1023) / 1024;

  // ---- CSR build: two-phase LDS bucket sort ----
  hipMemsetAsync(bcnt, 0, 256 * sizeof(int), stream);
  bhist_k<<<egrid4, 256, 0, stream>>>(ei, E0, Etot, bcnt);
  bscan_k<<<1, 256, 0, stream>>>(bcnt, bbase, bcur, Etot);
  bscat_k<<<egrid4, 256, 0, stream>>>(ei, E0, Etot, bcur, buck);
  bcsr_k<<<NB, 256, 0, stream>>>(buck, bbase, offs, srcs, N);

  // ---- weight packing for MFMA ----
  cvt_w_k<<<32, 256, 0, stream>>>(W1, Wmu, Wls, Bp1, Bp2);

  // ---- layer 1: GATConv(128 -> 4x64, concat) + bias + ReLU ----
  gemm1_mfma<<<MT, 256, 0, stream>>>(x, Bp1, aS1, aD1, h1bf, as1, ad1);
  gat_aggr1_k<<<(N + 1) / 2, 128, 0, stream>>>(offs, srcs, as1, ad1, h1bf, b1, Ap2, N);

  // ---- layers mu & logstd: GATConv(256 -> 1x64) + bias ----
  gemm2_mfma<<<(MT + 3) / 4, 256, 0, stream>>>(Ap2, Bp2, aSmu, aDmu, aSls, aDls,
                                               h2, as2m, ad2m, as2l, ad2l);
  gat_aggr2_k<<<(N + 1) / 2, 128, 0, stream>>>(offs, srcs, as2m, ad2m, as2l, ad2l,
                                               h2, bmu, bls, outmu, outls, N);
}

// Round 19
// 219.841 us; speedup vs baseline: 1.8742x; 1.0502x over previous
//
#include <hip/hip_runtime.h>
#include <hip/hip_bf16.h>

#define NNODES 50000
#define MT 3125              // NNODES / 16 row-tiles
#define NB 196               // ceil(NNODES / 256) dst-buckets
#define BCAP 5248            // bucket slab capacity (mean 4337, +13 sigma)
typedef __hip_bfloat16 bf16;
typedef __attribute__((ext_vector_type(8))) short bf16x8;  // 8 bf16 (4 VGPRs)
typedef __attribute__((ext_vector_type(4))) float f32x4;   // 4 f32 acc

__device__ __forceinline__ void unpack2(unsigned w, float& lo, float& hi){
  lo = __uint_as_float(w << 16);
  hi = __uint_as_float(w & 0xffff0000u);
}
__device__ __forceinline__ short f2bf(float f){
  union { __hip_bfloat16 h; short s; } u; u.h = __float2bfloat16(f); return u.s;
}
__device__ __forceinline__ float lrelu(float v){ return v > 0.f ? v : 0.2f * v; }

// ---------------- pack weights -> B-fragment bf16 ----------------
__global__ __launch_bounds__(256)
void cvt_w_k(const float* __restrict__ W1, const float* __restrict__ Wmu,
             const float* __restrict__ Wls, bf16x8* __restrict__ Bp1,
             bf16x8* __restrict__ Bp2){
  int t = blockIdx.x * 256 + threadIdx.x;
  if (t < 4096){
    int lane = t & 63, ct = (t >> 6) & 15, kt = t >> 10;
    int k0 = kt * 32 + (lane >> 4) * 8, col = ct * 16 + (lane & 15);
    bf16x8 o;
    #pragma unroll
    for (int j = 0; j < 8; j++) o[j] = f2bf(W1[(size_t)(k0 + j) * 256 + col]);
    Bp1[t] = o;
  } else if (t < 8192){
    int u = t - 4096;
    int lane = u & 63, ct = (u >> 6) & 7, kt = u >> 9;
    int k0 = kt * 32 + (lane >> 4) * 8, col = ct * 16 + (lane & 15);
    const float* W = (col < 64) ? Wmu : Wls;
    int cc = col & 63;
    bf16x8 o;
    #pragma unroll
    for (int j = 0; j < 8; j++) o[j] = f2bf(W[(size_t)(k0 + j) * 64 + cc]);
    Bp2[u] = o;
  }
}

// ------- MFMA GEMM 1 (reads f32 x directly) + fused alpha -------
__global__ __launch_bounds__(256)
void gemm1_mfma(const float* __restrict__ x, const bf16x8* __restrict__ Bp,
                const float* __restrict__ aS, const float* __restrict__ aD,
                bf16* __restrict__ Y, float* __restrict__ as1, float* __restrict__ ad1){
  int rt = blockIdx.x;
  int w = threadIdx.x >> 6, lane = threadIdx.x & 63;
  const float* xr = x + (size_t)(rt * 16 + (lane & 15)) * 128 + (lane >> 4) * 8;
  f32x4 z = {0.f, 0.f, 0.f, 0.f};
  f32x4 acc[4] = {z, z, z, z};
  for (int kt = 0; kt < 4; kt++){
    float4 v0 = *(const float4*)(xr + kt * 32);
    float4 v1 = *(const float4*)(xr + kt * 32 + 4);
    bf16x8 a;
    a[0] = f2bf(v0.x); a[1] = f2bf(v0.y); a[2] = f2bf(v0.z); a[3] = f2bf(v0.w);
    a[4] = f2bf(v1.x); a[5] = f2bf(v1.y); a[6] = f2bf(v1.z); a[7] = f2bf(v1.w);
    #pragma unroll
    for (int c = 0; c < 4; c++){
      bf16x8 b = Bp[(size_t)(kt * 16 + w * 4 + c) * 64 + lane];
      acc[c] = __builtin_amdgcn_mfma_f32_16x16x32_bf16(a, b, acc[c], 0, 0, 0);
    }
  }
  int row0 = rt * 16 + (lane >> 4) * 4;
  #pragma unroll
  for (int c = 0; c < 4; c++){
    int col = w * 64 + c * 16 + (lane & 15);
    #pragma unroll
    for (int i = 0; i < 4; i++)
      Y[(size_t)(row0 + i) * 256 + col] = __float2bfloat16(acc[c][i]);
  }
  float aSv[4], aDv[4];
  #pragma unroll
  for (int c = 0; c < 4; c++){
    int col = c * 16 + (lane & 15);
    aSv[c] = aS[w * 64 + col];
    aDv[c] = aD[w * 64 + col];
  }
  #pragma unroll
  for (int i = 0; i < 4; i++){
    float s1 = 0.f, s2 = 0.f;
    #pragma unroll
    for (int c = 0; c < 4; c++){
      s1 = fmaf(acc[c][i], aSv[c], s1);
      s2 = fmaf(acc[c][i], aDv[c], s2);
    }
    #pragma unroll
    for (int o = 1; o < 16; o <<= 1){
      s1 += __shfl_xor(s1, o);
      s2 += __shfl_xor(s2, o);
    }
    if ((lane & 15) == 0){
      int node = row0 + i;
      as1[node * 4 + w] = s1;
      ad1[node * 4 + w] = s2;
    }
  }
}

// ------- MFMA GEMM 2: one wave = one row-tile, BOTH branches + fused alphas -------
__global__ __launch_bounds__(256)
void gemm2_mfma(const bf16x8* __restrict__ Ap, const bf16x8* __restrict__ Bp,
                const float* __restrict__ aSmu, const float* __restrict__ aDmu,
                const float* __restrict__ aSls, const float* __restrict__ aDls,
                bf16* __restrict__ Y2,
                float* __restrict__ as2m, float* __restrict__ ad2m,
                float* __restrict__ as2l, float* __restrict__ ad2l){
  int w = threadIdx.x >> 6, lane = threadIdx.x & 63;
  int rt = blockIdx.x * 4 + w;
  if (rt >= MT) return;
  f32x4 z = {0.f, 0.f, 0.f, 0.f};
  f32x4 acc[8] = {z, z, z, z, z, z, z, z};   // 0-3 mu, 4-7 ls
  for (int kt = 0; kt < 8; kt++){
    bf16x8 a = Ap[(size_t)(rt * 8 + kt) * 64 + lane];
    #pragma unroll
    for (int c = 0; c < 8; c++){
      bf16x8 b = Bp[(size_t)(kt * 8 + c) * 64 + lane];
      acc[c] = __builtin_amdgcn_mfma_f32_16x16x32_bf16(a, b, acc[c], 0, 0, 0);
    }
  }
  int row0 = rt * 16 + (lane >> 4) * 4;
  #pragma unroll
  for (int c = 0; c < 4; c++){
    int col = c * 16 + (lane & 15);
    #pragma unroll
    for (int i = 0; i < 4; i++){
      Y2[(size_t)(row0 + i) * 128 + col]       = __float2bfloat16(acc[c][i]);
      Y2[(size_t)(row0 + i) * 128 + 64 + col]  = __float2bfloat16(acc[4 + c][i]);
    }
  }
  float aSm[4], aDm[4], aSl[4], aDl[4];
  #pragma unroll
  for (int c = 0; c < 4; c++){
    int col = c * 16 + (lane & 15);
    aSm[c] = aSmu[col]; aDm[c] = aDmu[col];
    aSl[c] = aSls[col]; aDl[c] = aDls[col];
  }
  #pragma unroll
  for (int i = 0; i < 4; i++){
    float s1 = 0.f, s2 = 0.f, s3 = 0.f, s4 = 0.f;
    #pragma unroll
    for (int c = 0; c < 4; c++){
      s1 = fmaf(acc[c][i], aSm[c], s1);
      s2 = fmaf(acc[c][i], aDm[c], s2);
      s3 = fmaf(acc[4 + c][i], aSl[c], s3);
      s4 = fmaf(acc[4 + c][i], aDl[c], s4);
    }
    #pragma unroll
    for (int o = 1; o < 16; o <<= 1){
      s1 += __shfl_xor(s1, o);
      s2 += __shfl_xor(s2, o);
      s3 += __shfl_xor(s3, o);
      s4 += __shfl_xor(s4, o);
    }
    if ((lane & 15) == 0){
      int node = row0 + i;
      as2m[node] = s1; ad2m[node] = s2;
      as2l[node] = s3; ad2l[node] = s4;
    }
  }
}

// ================ single-pass LDS bucket CSR build ================
// bscat: per-block LDS histogram + chunk reservation on bcnt (starts 0),
// writes packed edges into per-bucket SLABS buck[b*BCAP + ...]
__global__ __launch_bounds__(256)
void bscat_k(const int* __restrict__ ei, int E0, int Etot,
             int* __restrict__ bcnt, unsigned* __restrict__ buck){
  __shared__ int lh[NB];
  __shared__ int lbase[NB];
  for (int i = threadIdx.x; i < NB; i += 256) lh[i] = 0;
  __syncthreads();
  int base = blockIdx.x * 1024 + threadIdx.x;
  int sA[4], dA[4], rA[4];
  #pragma unroll
  for (int q = 0; q < 4; q++){
    int e = base + q * 256;
    sA[q] = -1;
    if (e < Etot){
      int s, d;
      if (e < E0){ s = ei[e]; d = ei[E0 + e]; } else { s = d = e - E0; }
      sA[q] = s; dA[q] = d;
      rA[q] = atomicAdd(&lh[d >> 8], 1);
    }
  }
  __syncthreads();
  for (int i = threadIdx.x; i < NB; i += 256)
    lbase[i] = lh[i] ? atomicAdd(&bcnt[i], lh[i]) : 0;
  __syncthreads();
  #pragma unroll
  for (int q = 0; q < 4; q++){
    if (sA[q] >= 0){
      int bk = dA[q] >> 8;
      buck[(size_t)bk * BCAP + lbase[bk] + rA[q]] =
          ((unsigned)(dA[q] & 255) << 16) | (unsigned)sA[q];
    }
  }
}

// exclusive scan over bucket counts -> bbase
__global__ __launch_bounds__(256)
void bscan_k(const int* __restrict__ bcnt, int* __restrict__ bbase, int total){
  __shared__ int buf[256];
  int t = threadIdx.x;
  int v = (t < NB) ? bcnt[t] : 0;
  buf[t] = v; __syncthreads();
  int acc = v;
  for (int off = 1; off < 256; off <<= 1){
    int x = (t >= off) ? buf[t - off] : 0;
    __syncthreads();
    acc += x; buf[t] = acc; __syncthreads();
  }
  if (t < NB) bbase[t] = acc - v;
  if (t == 0) bbase[NB] = total;
}

// per-bucket CSR finalize from slab
__global__ __launch_bounds__(256)
void bcsr_k(const unsigned* __restrict__ buck, const int* __restrict__ bcnt,
            const int* __restrict__ bbase,
            int* __restrict__ offs, int* __restrict__ srcs, int n){
  int b = blockIdx.x;
  int cntb = bcnt[b];
  int gbase = bbase[b];
  const unsigned* slab = buck + (size_t)b * BCAP;
  __shared__ int eh[256];
  __shared__ int buf[256];
  int t = threadIdx.x;
  eh[t] = 0;
  __syncthreads();
  for (int j = t; j < cntb; j += 256)
    atomicAdd(&eh[(slab[j] >> 16) & 255], 1);
  __syncthreads();
  int v = eh[t];
  buf[t] = v; __syncthreads();
  int acc = v;
  for (int off = 1; off < 256; off <<= 1){
    int x = (t >= off) ? buf[t - off] : 0;
    __syncthreads();
    acc += x; buf[t] = acc; __syncthreads();
  }
  int loff = acc - v;   // exclusive within bucket
  int node = b * 256 + t;
  if (node < n) offs[node] = gbase + loff;
  if (b == NB - 1 && t == 0) offs[n] = bbase[NB];
  __syncthreads();
  eh[t] = loff;        // reuse as cursors
  __syncthreads();
  for (int j = t; j < cntb; j += 256){
    unsigned val = slab[j];
    int dlo = (val >> 16) & 255;
    int rank = atomicAdd(&eh[dlo], 1);
    srcs[gbase + rank] = (int)(val & 0xffffu);
  }
}

// ------- aggregation layer 1: 2 nodes/block, pass-A max, BRANCH-FREE pass 2 -------
// clamp index (deg>=1 guaranteed by self-loop) so loads are unconditional ->
// compiler can software-pipeline; VGPR capped by launch_bounds(128,8)
__global__ __launch_bounds__(128, 8)
void gat_aggr1_k(const int* __restrict__ offs, const int* __restrict__ srcs,
                 const float* __restrict__ as, const float* __restrict__ ad,
                 const bf16* __restrict__ h, const float* __restrict__ b,
                 bf16x8* __restrict__ Ap2, int n){
  int node = blockIdx.x * 2 + (threadIdx.x >> 6);
  if (node >= n) return;
  int lane = threadIdx.x & 63;
  int beg = offs[node], end = offs[node + 1];
  int hA = lane >> 4, iA = lane & 15;
  float advA = ad[node * 4 + hA];
  float m = -1e30f;
  for (int j = beg + iA; j < end; j += 16)
    m = fmaxf(m, lrelu(as[srcs[j] * 4 + hA] + advA));
  #pragma unroll
  for (int o = 1; o < 16; o <<= 1) m = fmaxf(m, __shfl_xor(m, o));
  int hP = (lane >> 3) & 3, oct = lane & 7, slot = lane >> 5;
  float mP   = __shfl(m, hP * 16);
  float advP = __shfl(advA, hP * 16);
  float s = 0.f;
  float acc[8];
  #pragma unroll
  for (int i = 0; i < 8; i++) acc[i] = 0.f;
  #pragma unroll 8
  for (int j0 = beg; j0 < end; j0 += 2){
    int j = j0 + slot;
    bool val = j < end;
    int jc = val ? j : end - 1;
    int si = srcs[jc];
    float e = lrelu(as[si * 4 + hP] + advP);
    float p = val ? __expf(e - mP) : 0.f;
    s += p;
    uint4 dw = *(const uint4*)(h + (size_t)si * 256 + hP * 64 + oct * 8);
    float lo, hi;
    unpack2(dw.x, lo, hi); acc[0] = fmaf(lo, p, acc[0]); acc[1] = fmaf(hi, p, acc[1]);
    unpack2(dw.y, lo, hi); acc[2] = fmaf(lo, p, acc[2]); acc[3] = fmaf(hi, p, acc[3]);
    unpack2(dw.z, lo, hi); acc[4] = fmaf(lo, p, acc[4]); acc[5] = fmaf(hi, p, acc[5]);
    unpack2(dw.w, lo, hi); acc[6] = fmaf(lo, p, acc[6]); acc[7] = fmaf(hi, p, acc[7]);
  }
  s += __shfl_xor(s, 32);
  #pragma unroll
  for (int i = 0; i < 8; i++) acc[i] += __shfl_xor(acc[i], 32);
  if (lane < 32){
    float inv = 1.f / (s + 1e-16f);
    bf16x8 o;
    #pragma unroll
    for (int i = 0; i < 8; i++){
      float vv = acc[i] * inv + b[lane * 8 + i];
      o[i] = f2bf(vv > 0.f ? vv : 0.f);
    }
    int kt = lane >> 2, g = lane & 3;
    int rt = node >> 4, r = node & 15;
    Ap2[(size_t)(rt * 8 + kt) * 64 + g * 16 + r] = o;
  }
}

// ------- aggregation mu & logstd: interleaved h2, pass-A max, BRANCH-FREE pass 2 -------
__global__ __launch_bounds__(128, 8)
void gat_aggr2_k(const int* __restrict__ offs, const int* __restrict__ srcs,
                 const float* __restrict__ as2m, const float* __restrict__ ad2m,
                 const float* __restrict__ as2l, const float* __restrict__ ad2l,
                 const bf16* __restrict__ h2,
                 const float* __restrict__ bmu, const float* __restrict__ bls,
                 float* __restrict__ outmu, float* __restrict__ outls, int n){
  int node = blockIdx.x * 2 + (threadIdx.x >> 6);
  if (node >= n) return;
  int lane = threadIdx.x & 63;
  int beg = offs[node], end = offs[node + 1];
  const float* asA = (lane >= 32) ? as2l : as2m;
  float advA = ((lane >= 32) ? ad2l : ad2m)[node];
  int iA = lane & 31;
  float m = -1e30f;
  for (int j = beg + iA; j < end; j += 32)
    m = fmaxf(m, lrelu(asA[srcs[j]] + advA));
  #pragma unroll
  for (int o = 1; o < 32; o <<= 1) m = fmaxf(m, __shfl_xor(m, o));
  int br = (lane >> 3) & 1, oct = lane & 7, slot = lane >> 4;
  float mP   = __shfl(m, br * 32);
  float advP = __shfl(advA, br * 32);
  const float* asP = br ? as2l : as2m;
  float s = 0.f;
  float acc[8];
  #pragma unroll
  for (int i = 0; i < 8; i++) acc[i] = 0.f;
  #pragma unroll 8
  for (int j0 = beg; j0 < end; j0 += 4){
    int j = j0 + slot;
    bool val = j < end;
    int jc = val ? j : end - 1;
    int si = srcs[jc];
    float e = lrelu(asP[si] + advP);
    float p = val ? __expf(e - mP) : 0.f;
    s += p;
    uint4 dw = *(const uint4*)(h2 + (size_t)si * 128 + br * 64 + oct * 8);
    float lo, hi;
    unpack2(dw.x, lo, hi); acc[0] = fmaf(lo, p, acc[0]); acc[1] = fmaf(hi, p, acc[1]);
    unpack2(dw.y, lo, hi); acc[2] = fmaf(lo, p, acc[2]); acc[3] = fmaf(hi, p, acc[3]);
    unpack2(dw.z, lo, hi); acc[4] = fmaf(lo, p, acc[4]); acc[5] = fmaf(hi, p, acc[5]);
    unpack2(dw.w, lo, hi); acc[6] = fmaf(lo, p, acc[6]); acc[7] = fmaf(hi, p, acc[7]);
  }
  #pragma unroll
  for (int off = 16; off <= 32; off <<= 1){
    s += __shfl_xor(s, off);
    #pragma unroll
    for (int i = 0; i < 8; i++) acc[i] += __shfl_xor(acc[i], off);
  }
  if (lane < 16){
    float inv = 1.f / (s + 1e-16f);
    const float* bb = (lane >= 8) ? bls : bmu;
    float* out = (lane >= 8) ? outls : outmu;
    float v[8];
    #pragma unroll
    for (int i = 0; i < 8; i++) v[i] = acc[i] * inv + bb[oct * 8 + i];
    float* op = out + (size_t)node * 64 + oct * 8;
    *(float4*)op       = make_float4(v[0], v[1], v[2], v[3]);
    *(float4*)(op + 4) = make_float4(v[4], v[5], v[6], v[7]);
  }
}

extern "C" void kernel_launch(void* const* d_in, const int* in_sizes, int n_in,
                              void* d_out, int out_size, void* d_ws, size_t ws_size,
                              hipStream_t stream){
  const float* x    = (const float*)d_in[0];
  const int*   ei   = (const int*)d_in[1];
  const float* W1   = (const float*)d_in[2];
  const float* aS1  = (const float*)d_in[3];
  const float* aD1  = (const float*)d_in[4];
  const float* b1   = (const float*)d_in[5];
  const float* Wmu  = (const float*)d_in[6];
  const float* aSmu = (const float*)d_in[7];
  const float* aDmu = (const float*)d_in[8];
  const float* bmu  = (const float*)d_in[9];
  const float* Wls  = (const float*)d_in[10];
  const float* aSls = (const float*)d_in[11];
  const float* aDls = (const float*)d_in[12];
  const float* bls  = (const float*)d_in[13];

  const int N    = NNODES;
  const int E0   = in_sizes[1] / 2;
  const int Etot = E0 + N;

  // ---- workspace layout (float-unit offsets; bf16x8 arrays 16B-aligned) ----
  float* ws = (float*)d_ws;
  bf16x8* Ap2  = (bf16x8*)(ws);                 // [0, 6.4M): layer-1 out, packed A-frag
  bf16*   h1bf = (bf16*)(ws + 6400000);         // [6.4M, 12.8M): 12.8M bf16 row-major
  bf16*   h2   = (bf16*)(ws + 12800000);        // [12.8M, 16M): interleaved [N][128]
  float*  as1  = ws + 16000000;                 // 200K
  float*  ad1  = ws + 16200000;                 // 200K
  float*  as2m = ws + 16400000;                 // 50K each
  float*  ad2m = ws + 16450000;
  float*  as2l = ws + 16500000;
  float*  ad2l = ws + 16550000;
  int*      offs  = (int*)(ws + 16600000);      // 50001
  int*      srcs  = (int*)(ws + 16650016);      // 850000
  unsigned* buck  = (unsigned*)(ws + 17500016); // NB*BCAP = 1028608
  int*      bcnt  = (int*)(ws + 18528640);      // 256
  int*      bbase = (int*)(ws + 18528896);      // 257
  bf16x8*   Bp1   = (bf16x8*)(ws + 18529200);   // 32768 bf16 (16B-aligned)
  bf16x8*   Bp2   = (bf16x8*)(ws + 18545584);   // 32768 bf16

  float* outmu = (float*)d_out;
  float* outls = (float*)d_out + 3200000;

  const int egrid4 = (Etot + 1023) / 1024;

  // ---- CSR build: single-pass bucket slabs ----
  hipMemsetAsync(bcnt, 0, 256 * sizeof(int), stream);
  bscat_k<<<egrid4, 256, 0, stream>>>(ei, E0, Etot, bcnt, buck);
  bscan_k<<<1, 256, 0, stream>>>(bcnt, bbase, Etot);
  bcsr_k<<<NB, 256, 0, stream>>>(buck, bcnt, bbase, offs, srcs, N);

  // ---- weight packing for MFMA ----
  cvt_w_k<<<32, 256, 0, stream>>>(W1, Wmu, Wls, Bp1, Bp2);

  // ---- layer 1: GATConv(128 -> 4x64, concat) + bias + ReLU ----
  gemm1_mfma<<<MT, 256, 0, stream>>>(x, Bp1, aS1, aD1, h1bf, as1, ad1);
  gat_aggr1_k<<<(N + 1) / 2, 128, 0, stream>>>(offs, srcs, as1, ad1, h1bf, b1, Ap2, N);

  // ---- layers mu & logstd: GATConv(256 -> 1x64) + bias ----
  gemm2_mfma<<<(MT + 3) / 4, 256, 0, stream>>>(Ap2, Bp2, aSmu, aDmu, aSls, aDls,
                                               h2, as2m, ad2m, as2l, ad2l);
  gat_aggr2_k<<<(N + 1) / 2, 128, 0, stream>>>(offs, srcs, as2m, ad2m, as2l, ad2l,
                                               h2, bmu, bls, outmu, outls, N);
}

// Round 20
// 214.225 us; speedup vs baseline: 1.9234x; 1.0262x over previous
//
#include <hip/hip_runtime.h>
#include <hip/hip_bf16.h>

#define NNODES 50000
#define MT 3125              // NNODES / 16 row-tiles
#define NB 196               // ceil(NNODES / 256) dst-buckets
#define BCAP 5248            // bucket slab capacity (mean 4337, +13 sigma)
typedef __hip_bfloat16 bf16;
typedef __attribute__((ext_vector_type(8))) short bf16x8;  // 8 bf16 (4 VGPRs)
typedef __attribute__((ext_vector_type(4))) float f32x4;   // 4 f32 acc

__device__ __forceinline__ void unpack2(unsigned w, float& lo, float& hi){
  lo = __uint_as_float(w << 16);
  hi = __uint_as_float(w & 0xffff0000u);
}
__device__ __forceinline__ short f2bf(float f){
  union { __hip_bfloat16 h; short s; } u; u.h = __float2bfloat16(f); return u.s;
}
__device__ __forceinline__ float lrelu(float v){ return v > 0.f ? v : 0.2f * v; }

// ---------------- pack weights -> B-fragment bf16 ----------------
__global__ __launch_bounds__(256)
void cvt_w_k(const float* __restrict__ W1, const float* __restrict__ Wmu,
             const float* __restrict__ Wls, bf16x8* __restrict__ Bp1,
             bf16x8* __restrict__ Bp2){
  int t = blockIdx.x * 256 + threadIdx.x;
  if (t < 4096){
    int lane = t & 63, ct = (t >> 6) & 15, kt = t >> 10;
    int k0 = kt * 32 + (lane >> 4) * 8, col = ct * 16 + (lane & 15);
    bf16x8 o;
    #pragma unroll
    for (int j = 0; j < 8; j++) o[j] = f2bf(W1[(size_t)(k0 + j) * 256 + col]);
    Bp1[t] = o;
  } else if (t < 8192){
    int u = t - 4096;
    int lane = u & 63, ct = (u >> 6) & 7, kt = u >> 9;
    int k0 = kt * 32 + (lane >> 4) * 8, col = ct * 16 + (lane & 15);
    const float* W = (col < 64) ? Wmu : Wls;
    int cc = col & 63;
    bf16x8 o;
    #pragma unroll
    for (int j = 0; j < 8; j++) o[j] = f2bf(W[(size_t)(k0 + j) * 64 + cc]);
    Bp2[u] = o;
  }
}

// ------- MFMA GEMM 1 (reads f32 x directly) + fused alpha -------
__global__ __launch_bounds__(256)
void gemm1_mfma(const float* __restrict__ x, const bf16x8* __restrict__ Bp,
                const float* __restrict__ aS, const float* __restrict__ aD,
                bf16* __restrict__ Y, float* __restrict__ as1, float* __restrict__ ad1){
  int rt = blockIdx.x;
  int w = threadIdx.x >> 6, lane = threadIdx.x & 63;
  const float* xr = x + (size_t)(rt * 16 + (lane & 15)) * 128 + (lane >> 4) * 8;
  f32x4 z = {0.f, 0.f, 0.f, 0.f};
  f32x4 acc[4] = {z, z, z, z};
  for (int kt = 0; kt < 4; kt++){
    float4 v0 = *(const float4*)(xr + kt * 32);
    float4 v1 = *(const float4*)(xr + kt * 32 + 4);
    bf16x8 a;
    a[0] = f2bf(v0.x); a[1] = f2bf(v0.y); a[2] = f2bf(v0.z); a[3] = f2bf(v0.w);
    a[4] = f2bf(v1.x); a[5] = f2bf(v1.y); a[6] = f2bf(v1.z); a[7] = f2bf(v1.w);
    #pragma unroll
    for (int c = 0; c < 4; c++){
      bf16x8 b = Bp[(size_t)(kt * 16 + w * 4 + c) * 64 + lane];
      acc[c] = __builtin_amdgcn_mfma_f32_16x16x32_bf16(a, b, acc[c], 0, 0, 0);
    }
  }
  int row0 = rt * 16 + (lane >> 4) * 4;
  #pragma unroll
  for (int c = 0; c < 4; c++){
    int col = w * 64 + c * 16 + (lane & 15);
    #pragma unroll
    for (int i = 0; i < 4; i++)
      Y[(size_t)(row0 + i) * 256 + col] = __float2bfloat16(acc[c][i]);
  }
  float aSv[4], aDv[4];
  #pragma unroll
  for (int c = 0; c < 4; c++){
    int col = c * 16 + (lane & 15);
    aSv[c] = aS[w * 64 + col];
    aDv[c] = aD[w * 64 + col];
  }
  #pragma unroll
  for (int i = 0; i < 4; i++){
    float s1 = 0.f, s2 = 0.f;
    #pragma unroll
    for (int c = 0; c < 4; c++){
      s1 = fmaf(acc[c][i], aSv[c], s1);
      s2 = fmaf(acc[c][i], aDv[c], s2);
    }
    #pragma unroll
    for (int o = 1; o < 16; o <<= 1){
      s1 += __shfl_xor(s1, o);
      s2 += __shfl_xor(s2, o);
    }
    if ((lane & 15) == 0){
      int node = row0 + i;
      as1[node * 4 + w] = s1;
      ad1[node * 4 + w] = s2;
    }
  }
}

// ------- MFMA GEMM 2: one wave = one row-tile, BOTH branches + fused alphas -------
// writes interleaved h2[node][128]: cols 0-63 mu, 64-127 ls
__global__ __launch_bounds__(256)
void gemm2_mfma(const bf16x8* __restrict__ Ap, const bf16x8* __restrict__ Bp,
                const float* __restrict__ aSmu, const float* __restrict__ aDmu,
                const float* __restrict__ aSls, const float* __restrict__ aDls,
                bf16* __restrict__ Y2,
                float* __restrict__ as2m, float* __restrict__ ad2m,
                float* __restrict__ as2l, float* __restrict__ ad2l){
  int w = threadIdx.x >> 6, lane = threadIdx.x & 63;
  int rt = blockIdx.x * 4 + w;
  if (rt >= MT) return;
  f32x4 z = {0.f, 0.f, 0.f, 0.f};
  f32x4 acc[8] = {z, z, z, z, z, z, z, z};   // 0-3 mu, 4-7 ls
  for (int kt = 0; kt < 8; kt++){
    bf16x8 a = Ap[(size_t)(rt * 8 + kt) * 64 + lane];
    #pragma unroll
    for (int c = 0; c < 8; c++){
      bf16x8 b = Bp[(size_t)(kt * 8 + c) * 64 + lane];
      acc[c] = __builtin_amdgcn_mfma_f32_16x16x32_bf16(a, b, acc[c], 0, 0, 0);
    }
  }
  int row0 = rt * 16 + (lane >> 4) * 4;
  #pragma unroll
  for (int c = 0; c < 4; c++){
    int col = c * 16 + (lane & 15);
    #pragma unroll
    for (int i = 0; i < 4; i++){
      Y2[(size_t)(row0 + i) * 128 + col]       = __float2bfloat16(acc[c][i]);
      Y2[(size_t)(row0 + i) * 128 + 64 + col]  = __float2bfloat16(acc[4 + c][i]);
    }
  }
  float aSm[4], aDm[4], aSl[4], aDl[4];
  #pragma unroll
  for (int c = 0; c < 4; c++){
    int col = c * 16 + (lane & 15);
    aSm[c] = aSmu[col]; aDm[c] = aDmu[col];
    aSl[c] = aSls[col]; aDl[c] = aDls[col];
  }
  #pragma unroll
  for (int i = 0; i < 4; i++){
    float s1 = 0.f, s2 = 0.f, s3 = 0.f, s4 = 0.f;
    #pragma unroll
    for (int c = 0; c < 4; c++){
      s1 = fmaf(acc[c][i], aSm[c], s1);
      s2 = fmaf(acc[c][i], aDm[c], s2);
      s3 = fmaf(acc[4 + c][i], aSl[c], s3);
      s4 = fmaf(acc[4 + c][i], aDl[c], s4);
    }
    #pragma unroll
    for (int o = 1; o < 16; o <<= 1){
      s1 += __shfl_xor(s1, o);
      s2 += __shfl_xor(s2, o);
      s3 += __shfl_xor(s3, o);
      s4 += __shfl_xor(s4, o);
    }
    if ((lane & 15) == 0){
      int node = row0 + i;
      as2m[node] = s1; ad2m[node] = s2;
      as2l[node] = s3; ad2l[node] = s4;
    }
  }
}

// ================ single-pass LDS bucket CSR build ================
__global__ __launch_bounds__(256)
void bscat_k(const int* __restrict__ ei, int E0, int Etot,
             int* __restrict__ bcnt, unsigned* __restrict__ buck){
  __shared__ int lh[NB];
  __shared__ int lbase[NB];
  for (int i = threadIdx.x; i < NB; i += 256) lh[i] = 0;
  __syncthreads();
  int base = blockIdx.x * 1024 + threadIdx.x;
  int sA[4], dA[4], rA[4];
  #pragma unroll
  for (int q = 0; q < 4; q++){
    int e = base + q * 256;
    sA[q] = -1;
    if (e < Etot){
      int s, d;
      if (e < E0){ s = ei[e]; d = ei[E0 + e]; } else { s = d = e - E0; }
      sA[q] = s; dA[q] = d;
      rA[q] = atomicAdd(&lh[d >> 8], 1);
    }
  }
  __syncthreads();
  for (int i = threadIdx.x; i < NB; i += 256)
    lbase[i] = lh[i] ? atomicAdd(&bcnt[i], lh[i]) : 0;
  __syncthreads();
  #pragma unroll
  for (int q = 0; q < 4; q++){
    if (sA[q] >= 0){
      int bk = dA[q] >> 8;
      buck[(size_t)bk * BCAP + lbase[bk] + rA[q]] =
          ((unsigned)(dA[q] & 255) << 16) | (unsigned)sA[q];
    }
  }
}

__global__ __launch_bounds__(256)
void bscan_k(const int* __restrict__ bcnt, int* __restrict__ bbase, int total){
  __shared__ int buf[256];
  int t = threadIdx.x;
  int v = (t < NB) ? bcnt[t] : 0;
  buf[t] = v; __syncthreads();
  int acc = v;
  for (int off = 1; off < 256; off <<= 1){
    int x = (t >= off) ? buf[t - off] : 0;
    __syncthreads();
    acc += x; buf[t] = acc; __syncthreads();
  }
  if (t < NB) bbase[t] = acc - v;
  if (t == 0) bbase[NB] = total;
}

__global__ __launch_bounds__(256)
void bcsr_k(const unsigned* __restrict__ buck, const int* __restrict__ bcnt,
            const int* __restrict__ bbase,
            int* __restrict__ offs, int* __restrict__ srcs, int n){
  int b = blockIdx.x;
  int cntb = bcnt[b];
  int gbase = bbase[b];
  const unsigned* slab = buck + (size_t)b * BCAP;
  __shared__ int eh[256];
  __shared__ int buf[256];
  int t = threadIdx.x;
  eh[t] = 0;
  __syncthreads();
  for (int j = t; j < cntb; j += 256)
    atomicAdd(&eh[(slab[j] >> 16) & 255], 1);
  __syncthreads();
  int v = eh[t];
  buf[t] = v; __syncthreads();
  int acc = v;
  for (int off = 1; off < 256; off <<= 1){
    int x = (t >= off) ? buf[t - off] : 0;
    __syncthreads();
    acc += x; buf[t] = acc; __syncthreads();
  }
  int loff = acc - v;   // exclusive within bucket
  int node = b * 256 + t;
  if (node < n) offs[node] = gbase + loff;
  if (b == NB - 1 && t == 0) offs[n] = bbase[NB];
  __syncthreads();
  eh[t] = loff;        // reuse as cursors
  __syncthreads();
  for (int j = t; j < cntb; j += 256){
    unsigned val = slab[j];
    int dlo = (val >> 16) & 255;
    int rank = atomicAdd(&eh[dlo], 1);
    srcs[gbase + rank] = (int)(val & 0xffffu);
  }
}

// ------- aggregation layer 1: 2 nodes/block, pass-A max, predicated pass 2 (R18) -------
__global__ __launch_bounds__(128)
void gat_aggr1_k(const int* __restrict__ offs, const int* __restrict__ srcs,
                 const float* __restrict__ as, const float* __restrict__ ad,
                 const bf16* __restrict__ h, const float* __restrict__ b,
                 bf16x8* __restrict__ Ap2, int n){
  int node = blockIdx.x * 2 + (threadIdx.x >> 6);
  if (node >= n) return;
  int lane = threadIdx.x & 63;
  int beg = offs[node], end = offs[node + 1];
  int hA = lane >> 4, iA = lane & 15;
  float advA = ad[node * 4 + hA];
  float m = -1e30f;
  for (int j = beg + iA; j < end; j += 16)
    m = fmaxf(m, lrelu(as[srcs[j] * 4 + hA] + advA));
  #pragma unroll
  for (int o = 1; o < 16; o <<= 1) m = fmaxf(m, __shfl_xor(m, o));
  int hP = (lane >> 3) & 3, oct = lane & 7, slot = lane >> 5;
  float mP   = __shfl(m, hP * 16);
  float advP = __shfl(advA, hP * 16);
  float s = 0.f;
  float acc[8];
  #pragma unroll
  for (int i = 0; i < 8; i++) acc[i] = 0.f;
  #pragma unroll 8
  for (int j0 = beg; j0 < end; j0 += 2){
    int j = j0 + slot;
    if (j < end){
      int si = srcs[j];
      float e = lrelu(as[si * 4 + hP] + advP);
      float p = __expf(e - mP);
      s += p;
      uint4 dw = *(const uint4*)(h + (size_t)si * 256 + hP * 64 + oct * 8);
      float lo, hi;
      unpack2(dw.x, lo, hi); acc[0] = fmaf(lo, p, acc[0]); acc[1] = fmaf(hi, p, acc[1]);
      unpack2(dw.y, lo, hi); acc[2] = fmaf(lo, p, acc[2]); acc[3] = fmaf(hi, p, acc[3]);
      unpack2(dw.z, lo, hi); acc[4] = fmaf(lo, p, acc[4]); acc[5] = fmaf(hi, p, acc[5]);
      unpack2(dw.w, lo, hi); acc[6] = fmaf(lo, p, acc[6]); acc[7] = fmaf(hi, p, acc[7]);
    }
  }
  s += __shfl_xor(s, 32);
  #pragma unroll
  for (int i = 0; i < 8; i++) acc[i] += __shfl_xor(acc[i], 32);
  if (lane < 32){
    float inv = 1.f / (s + 1e-16f);
    bf16x8 o;
    #pragma unroll
    for (int i = 0; i < 8; i++){
      float vv = acc[i] * inv + b[lane * 8 + i];
      o[i] = f2bf(vv > 0.f ? vv : 0.f);
    }
    int kt = lane >> 2, g = lane & 3;
    int rt = node >> 4, r = node & 15;
    Ap2[(size_t)(rt * 8 + kt) * 64 + g * 16 + r] = o;
  }
}

// ------- aggregation mu & logstd: interleaved h2, pass-A max, predicated unroll-8 (R18) -------
__global__ __launch_bounds__(128)
void gat_aggr2_k(const int* __restrict__ offs, const int* __restrict__ srcs,
                 const float* __restrict__ as2m, const float* __restrict__ ad2m,
                 const float* __restrict__ as2l, const float* __restrict__ ad2l,
                 const bf16* __restrict__ h2,
                 const float* __restrict__ bmu, const float* __restrict__ bls,
                 float* __restrict__ outmu, float* __restrict__ outls, int n){
  int node = blockIdx.x * 2 + (threadIdx.x >> 6);
  if (node >= n) return;
  int lane = threadIdx.x & 63;
  int beg = offs[node], end = offs[node + 1];
  const float* asA = (lane >= 32) ? as2l : as2m;
  float advA = ((lane >= 32) ? ad2l : ad2m)[node];
  int iA = lane & 31;
  float m = -1e30f;
  for (int j = beg + iA; j < end; j += 32)
    m = fmaxf(m, lrelu(asA[srcs[j]] + advA));
  #pragma unroll
  for (int o = 1; o < 32; o <<= 1) m = fmaxf(m, __shfl_xor(m, o));
  int br = (lane >> 3) & 1, oct = lane & 7, slot = lane >> 4;
  float mP   = __shfl(m, br * 32);
  float advP = __shfl(advA, br * 32);
  const float* asP = br ? as2l : as2m;
  float s = 0.f;
  float acc[8];
  #pragma unroll
  for (int i = 0; i < 8; i++) acc[i] = 0.f;
  #pragma unroll 8
  for (int j0 = beg; j0 < end; j0 += 4){
    int j = j0 + slot;
    if (j < end){
      int si = srcs[j];
      float e = lrelu(asP[si] + advP);
      float p = __expf(e - mP);
      s += p;
      uint4 dw = *(const uint4*)(h2 + (size_t)si * 128 + br * 64 + oct * 8);
      float lo, hi;
      unpack2(dw.x, lo, hi); acc[0] = fmaf(lo, p, acc[0]); acc[1] = fmaf(hi, p, acc[1]);
      unpack2(dw.y, lo, hi); acc[2] = fmaf(lo, p, acc[2]); acc[3] = fmaf(hi, p, acc[3]);
      unpack2(dw.z, lo, hi); acc[4] = fmaf(lo, p, acc[4]); acc[5] = fmaf(hi, p, acc[5]);
      unpack2(dw.w, lo, hi); acc[6] = fmaf(lo, p, acc[6]); acc[7] = fmaf(hi, p, acc[7]);
    }
  }
  #pragma unroll
  for (int off = 16; off <= 32; off <<= 1){
    s += __shfl_xor(s, off);
    #pragma unroll
    for (int i = 0; i < 8; i++) acc[i] += __shfl_xor(acc[i], off);
  }
  if (lane < 16){
    float inv = 1.f / (s + 1e-16f);
    const float* bb = (lane >= 8) ? bls : bmu;
    float* out = (lane >= 8) ? outls : outmu;
    float v[8];
    #pragma unroll
    for (int i = 0; i < 8; i++) v[i] = acc[i] * inv + bb[oct * 8 + i];
    float* op = out + (size_t)node * 64 + oct * 8;
    *(float4*)op       = make_float4(v[0], v[1], v[2], v[3]);
    *(float4*)(op + 4) = make_float4(v[4], v[5], v[6], v[7]);
  }
}

extern "C" void kernel_launch(void* const* d_in, const int* in_sizes, int n_in,
                              void* d_out, int out_size, void* d_ws, size_t ws_size,
                              hipStream_t stream){
  const float* x    = (const float*)d_in[0];
  const int*   ei   = (const int*)d_in[1];
  const float* W1   = (const float*)d_in[2];
  const float* aS1  = (const float*)d_in[3];
  const float* aD1  = (const float*)d_in[4];
  const float* b1   = (const float*)d_in[5];
  const float* Wmu  = (const float*)d_in[6];
  const float* aSmu = (const float*)d_in[7];
  const float* aDmu = (const float*)d_in[8];
  const float* bmu  = (const float*)d_in[9];
  const float* Wls  = (const float*)d_in[10];
  const float* aSls = (const float*)d_in[11];
  const float* aDls = (const float*)d_in[12];
  const float* bls  = (const float*)d_in[13];

  const int N    = NNODES;
  const int E0   = in_sizes[1] / 2;
  const int Etot = E0 + N;

  // ---- workspace layout (float-unit offsets; bf16x8 arrays 16B-aligned) ----
  float* ws = (float*)d_ws;
  bf16x8* Ap2  = (bf16x8*)(ws);                 // [0, 6.4M): layer-1 out, packed A-frag
  bf16*   h1bf = (bf16*)(ws + 6400000);         // [6.4M, 12.8M): 12.8M bf16 row-major
  bf16*   h2   = (bf16*)(ws + 12800000);        // [12.8M, 16M): interleaved [N][128]
  float*  as1  = ws + 16000000;                 // 200K
  float*  ad1  = ws + 16200000;                 // 200K
  float*  as2m = ws + 16400000;                 // 50K each
  float*  ad2m = ws + 16450000;
  float*  as2l = ws + 16500000;
  float*  ad2l = ws + 16550000;
  int*      offs  = (int*)(ws + 16600000);      // 50001
  int*      srcs  = (int*)(ws + 16650016);      // 850000
  unsigned* buck  = (unsigned*)(ws + 17500016); // NB*BCAP = 1028608
  int*      bcnt  = (int*)(ws + 18528640);      // 256
  int*      bbase = (int*)(ws + 18528896);      // 257
  bf16x8*   Bp1   = (bf16x8*)(ws + 18529200);   // 32768 bf16 (16B-aligned)
  bf16x8*   Bp2   = (bf16x8*)(ws + 18545584);   // 32768 bf16

  float* outmu = (float*)d_out;
  float* outls = (float*)d_out + 3200000;

  const int egrid4 = (Etot + 1023) / 1024;

  // ---- CSR build: single-pass bucket slabs ----
  hipMemsetAsync(bcnt, 0, 256 * sizeof(int), stream);
  bscat_k<<<egrid4, 256, 0, stream>>>(ei, E0, Etot, bcnt, buck);
  bscan_k<<<1, 256, 0, stream>>>(bcnt, bbase, Etot);
  bcsr_k<<<NB, 256, 0, stream>>>(buck, bcnt, bbase, offs, srcs, N);

  // ---- weight packing for MFMA ----
  cvt_w_k<<<32, 256, 0, stream>>>(W1, Wmu, Wls, Bp1, Bp2);

  // ---- layer 1: GATConv(128 -> 4x64, concat) + bias + ReLU ----
  gemm1_mfma<<<MT, 256, 0, stream>>>(x, Bp1, aS1, aD1, h1bf, as1, ad1);
  gat_aggr1_k<<<(N + 1) / 2, 128, 0, stream>>>(offs, srcs, as1, ad1, h1bf, b1, Ap2, N);

  // ---- layers mu & logstd: GATConv(256 -> 1x64) + bias ----
  gemm2_mfma<<<(MT + 3) / 4, 256, 0, stream>>>(Ap2, Bp2, aSmu, aDmu, aSls, aDls,
                                               h2, as2m, ad2m, as2l, ad2l);
  gat_aggr2_k<<<(N + 1) / 2, 128, 0, stream>>>(offs, srcs, as2m, ad2m, as2l, ad2l,
                                               h2, bmu, bls, outmu, outls, N);
}

// Round 21
// 213.328 us; speedup vs baseline: 1.9314x; 1.0042x over previous
//
#include <hip/hip_runtime.h>
#include <hip/hip_bf16.h>

#define NNODES 50000
#define MT 3125              // NNODES / 16 row-tiles
#define NB 196               // ceil(NNODES / 256) dst-buckets
#define BCAP 5248            // bucket slab capacity (mean 4337, +13 sigma)
typedef __hip_bfloat16 bf16;
typedef __attribute__((ext_vector_type(8))) short bf16x8;  // 8 bf16 (4 VGPRs)
typedef __attribute__((ext_vector_type(4))) float f32x4;   // 4 f32 acc

__device__ __forceinline__ void unpack2(unsigned w, float& lo, float& hi){
  lo = __uint_as_float(w << 16);
  hi = __uint_as_float(w & 0xffff0000u);
}
__device__ __forceinline__ short f2bf(float f){
  union { __hip_bfloat16 h; short s; } u; u.h = __float2bfloat16(f); return u.s;
}
__device__ __forceinline__ float lrelu(float v){ return v > 0.f ? v : 0.2f * v; }

// ---------------- pack weights -> B-fragment bf16 ----------------
__global__ __launch_bounds__(256)
void cvt_w_k(const float* __restrict__ W1, const float* __restrict__ Wmu,
             const float* __restrict__ Wls, bf16x8* __restrict__ Bp1,
             bf16x8* __restrict__ Bp2){
  int t = blockIdx.x * 256 + threadIdx.x;
  if (t < 4096){
    int lane = t & 63, ct = (t >> 6) & 15, kt = t >> 10;
    int k0 = kt * 32 + (lane >> 4) * 8, col = ct * 16 + (lane & 15);
    bf16x8 o;
    #pragma unroll
    for (int j = 0; j < 8; j++) o[j] = f2bf(W1[(size_t)(k0 + j) * 256 + col]);
    Bp1[t] = o;
  } else if (t < 8192){
    int u = t - 4096;
    int lane = u & 63, ct = (u >> 6) & 7, kt = u >> 9;
    int k0 = kt * 32 + (lane >> 4) * 8, col = ct * 16 + (lane & 15);
    const float* W = (col < 64) ? Wmu : Wls;
    int cc = col & 63;
    bf16x8 o;
    #pragma unroll
    for (int j = 0; j < 8; j++) o[j] = f2bf(W[(size_t)(k0 + j) * 64 + cc]);
    Bp2[u] = o;
  }
}

// ------- MFMA GEMM 1 (reads f32 x directly) + fused alpha -------
__global__ __launch_bounds__(256)
void gemm1_mfma(const float* __restrict__ x, const bf16x8* __restrict__ Bp,
                const float* __restrict__ aS, const float* __restrict__ aD,
                bf16* __restrict__ Y, float* __restrict__ as1, float* __restrict__ ad1){
  int rt = blockIdx.x;
  int w = threadIdx.x >> 6, lane = threadIdx.x & 63;
  const float* xr = x + (size_t)(rt * 16 + (lane & 15)) * 128 + (lane >> 4) * 8;
  f32x4 z = {0.f, 0.f, 0.f, 0.f};
  f32x4 acc[4] = {z, z, z, z};
  for (int kt = 0; kt < 4; kt++){
    float4 v0 = *(const float4*)(xr + kt * 32);
    float4 v1 = *(const float4*)(xr + kt * 32 + 4);
    bf16x8 a;
    a[0] = f2bf(v0.x); a[1] = f2bf(v0.y); a[2] = f2bf(v0.z); a[3] = f2bf(v0.w);
    a[4] = f2bf(v1.x); a[5] = f2bf(v1.y); a[6] = f2bf(v1.z); a[7] = f2bf(v1.w);
    #pragma unroll
    for (int c = 0; c < 4; c++){
      bf16x8 b = Bp[(size_t)(kt * 16 + w * 4 + c) * 64 + lane];
      acc[c] = __builtin_amdgcn_mfma_f32_16x16x32_bf16(a, b, acc[c], 0, 0, 0);
    }
  }
  int row0 = rt * 16 + (lane >> 4) * 4;
  #pragma unroll
  for (int c = 0; c < 4; c++){
    int col = w * 64 + c * 16 + (lane & 15);
    #pragma unroll
    for (int i = 0; i < 4; i++)
      Y[(size_t)(row0 + i) * 256 + col] = __float2bfloat16(acc[c][i]);
  }
  float aSv[4], aDv[4];
  #pragma unroll
  for (int c = 0; c < 4; c++){
    int col = c * 16 + (lane & 15);
    aSv[c] = aS[w * 64 + col];
    aDv[c] = aD[w * 64 + col];
  }
  #pragma unroll
  for (int i = 0; i < 4; i++){
    float s1 = 0.f, s2 = 0.f;
    #pragma unroll
    for (int c = 0; c < 4; c++){
      s1 = fmaf(acc[c][i], aSv[c], s1);
      s2 = fmaf(acc[c][i], aDv[c], s2);
    }
    #pragma unroll
    for (int o = 1; o < 16; o <<= 1){
      s1 += __shfl_xor(s1, o);
      s2 += __shfl_xor(s2, o);
    }
    if ((lane & 15) == 0){
      int node = row0 + i;
      as1[node * 4 + w] = s1;
      ad1[node * 4 + w] = s2;
    }
  }
}

// ------- MFMA GEMM 2: one wave = one row-tile, BOTH branches + fused alphas -------
// writes interleaved h2[node][128]: cols 0-63 mu, 64-127 ls
__global__ __launch_bounds__(256)
void gemm2_mfma(const bf16x8* __restrict__ Ap, const bf16x8* __restrict__ Bp,
                const float* __restrict__ aSmu, const float* __restrict__ aDmu,
                const float* __restrict__ aSls, const float* __restrict__ aDls,
                bf16* __restrict__ Y2,
                float* __restrict__ as2m, float* __restrict__ ad2m,
                float* __restrict__ as2l, float* __restrict__ ad2l){
  int w = threadIdx.x >> 6, lane = threadIdx.x & 63;
  int rt = blockIdx.x * 4 + w;
  if (rt >= MT) return;
  f32x4 z = {0.f, 0.f, 0.f, 0.f};
  f32x4 acc[8] = {z, z, z, z, z, z, z, z};   // 0-3 mu, 4-7 ls
  for (int kt = 0; kt < 8; kt++){
    bf16x8 a = Ap[(size_t)(rt * 8 + kt) * 64 + lane];
    #pragma unroll
    for (int c = 0; c < 8; c++){
      bf16x8 b = Bp[(size_t)(kt * 8 + c) * 64 + lane];
      acc[c] = __builtin_amdgcn_mfma_f32_16x16x32_bf16(a, b, acc[c], 0, 0, 0);
    }
  }
  int row0 = rt * 16 + (lane >> 4) * 4;
  #pragma unroll
  for (int c = 0; c < 4; c++){
    int col = c * 16 + (lane & 15);
    #pragma unroll
    for (int i = 0; i < 4; i++){
      Y2[(size_t)(row0 + i) * 128 + col]       = __float2bfloat16(acc[c][i]);
      Y2[(size_t)(row0 + i) * 128 + 64 + col]  = __float2bfloat16(acc[4 + c][i]);
    }
  }
  float aSm[4], aDm[4], aSl[4], aDl[4];
  #pragma unroll
  for (int c = 0; c < 4; c++){
    int col = c * 16 + (lane & 15);
    aSm[c] = aSmu[col]; aDm[c] = aDmu[col];
    aSl[c] = aSls[col]; aDl[c] = aDls[col];
  }
  #pragma unroll
  for (int i = 0; i < 4; i++){
    float s1 = 0.f, s2 = 0.f, s3 = 0.f, s4 = 0.f;
    #pragma unroll
    for (int c = 0; c < 4; c++){
      s1 = fmaf(acc[c][i], aSm[c], s1);
      s2 = fmaf(acc[c][i], aDm[c], s2);
      s3 = fmaf(acc[4 + c][i], aSl[c], s3);
      s4 = fmaf(acc[4 + c][i], aDl[c], s4);
    }
    #pragma unroll
    for (int o = 1; o < 16; o <<= 1){
      s1 += __shfl_xor(s1, o);
      s2 += __shfl_xor(s2, o);
      s3 += __shfl_xor(s3, o);
      s4 += __shfl_xor(s4, o);
    }
    if ((lane & 15) == 0){
      int node = row0 + i;
      as2m[node] = s1; ad2m[node] = s2;
      as2l[node] = s3; ad2l[node] = s4;
    }
  }
}

// ================ single-pass LDS bucket CSR build ================
__global__ __launch_bounds__(256)
void bscat_k(const int* __restrict__ ei, int E0, int Etot,
             int* __restrict__ bcnt, unsigned* __restrict__ buck){
  __shared__ int lh[NB];
  __shared__ int lbase[NB];
  for (int i = threadIdx.x; i < NB; i += 256) lh[i] = 0;
  __syncthreads();
  int base = blockIdx.x * 1024 + threadIdx.x;
  int sA[4], dA[4], rA[4];
  #pragma unroll
  for (int q = 0; q < 4; q++){
    int e = base + q * 256;
    sA[q] = -1;
    if (e < Etot){
      int s, d;
      if (e < E0){ s = ei[e]; d = ei[E0 + e]; } else { s = d = e - E0; }
      sA[q] = s; dA[q] = d;
      rA[q] = atomicAdd(&lh[d >> 8], 1);
    }
  }
  __syncthreads();
  for (int i = threadIdx.x; i < NB; i += 256)
    lbase[i] = lh[i] ? atomicAdd(&bcnt[i], lh[i]) : 0;
  __syncthreads();
  #pragma unroll
  for (int q = 0; q < 4; q++){
    if (sA[q] >= 0){
      int bk = dA[q] >> 8;
      buck[(size_t)bk * BCAP + lbase[bk] + rA[q]] =
          ((unsigned)(dA[q] & 255) << 16) | (unsigned)sA[q];
    }
  }
}

// per-bucket CSR finalize; computes its own bucket-prefix from bcnt (no bscan pass)
__global__ __launch_bounds__(256)
void bcsr_k(const unsigned* __restrict__ buck, const int* __restrict__ bcnt,
            int* __restrict__ offs, int* __restrict__ srcs, int n, int total){
  int b = blockIdx.x;
  __shared__ int eh[256];
  __shared__ int buf[256];
  int t = threadIdx.x;
  // inline exclusive prefix over bucket counts
  int bv = (t < NB) ? bcnt[t] : 0;
  buf[t] = bv; __syncthreads();
  int bacc = bv;
  for (int off = 1; off < 256; off <<= 1){
    int x = (t >= off) ? buf[t - off] : 0;
    __syncthreads();
    bacc += x; buf[t] = bacc; __syncthreads();
  }
  int gbase = (b == 0) ? 0 : buf[b - 1];   // inclusive scan -> exclusive base
  int cntb  = bcnt[b];
  const unsigned* slab = buck + (size_t)b * BCAP;
  __syncthreads();
  eh[t] = 0;
  __syncthreads();
  for (int j = t; j < cntb; j += 256)
    atomicAdd(&eh[(slab[j] >> 16) & 255], 1);
  __syncthreads();
  int v = eh[t];
  buf[t] = v; __syncthreads();
  int acc = v;
  for (int off = 1; off < 256; off <<= 1){
    int x = (t >= off) ? buf[t - off] : 0;
    __syncthreads();
    acc += x; buf[t] = acc; __syncthreads();
  }
  int loff = acc - v;   // exclusive within bucket
  int node = b * 256 + t;
  if (node < n) offs[node] = gbase + loff;
  if (b == NB - 1 && t == 0) offs[n] = total;
  __syncthreads();
  eh[t] = loff;        // reuse as cursors
  __syncthreads();
  for (int j = t; j < cntb; j += 256){
    unsigned val = slab[j];
    int dlo = (val >> 16) & 255;
    int rank = atomicAdd(&eh[dlo], 1);
    srcs[gbase + rank] = (int)(val & 0xffffu);
  }
}

// ------- aggregation layer 1: 2 nodes/block, pass-A max, MANUAL 2-stage pipeline -------
__global__ __launch_bounds__(128)
void gat_aggr1_k(const int* __restrict__ offs, const int* __restrict__ srcs,
                 const float* __restrict__ as, const float* __restrict__ ad,
                 const bf16* __restrict__ h, const float* __restrict__ b,
                 bf16x8* __restrict__ Ap2, int n){
  int node = blockIdx.x * 2 + (threadIdx.x >> 6);
  if (node >= n) return;
  int lane = threadIdx.x & 63;
  int beg = offs[node], end = offs[node + 1];
  int hA = lane >> 4, iA = lane & 15;
  float advA = ad[node * 4 + hA];
  float m = -1e30f;
  for (int j = beg + iA; j < end; j += 16)
    m = fmaxf(m, lrelu(as[srcs[j] * 4 + hA] + advA));
  #pragma unroll
  for (int o = 1; o < 16; o <<= 1) m = fmaxf(m, __shfl_xor(m, o));
  int hP = (lane >> 3) & 3, oct = lane & 7, slot = lane >> 5;
  float mP   = __shfl(m, hP * 16);
  float advP = __shfl(advA, hP * 16);
  float s = 0.f;
  float acc[8];
  #pragma unroll
  for (int i = 0; i < 8; i++) acc[i] = 0.f;
  // software-pipelined: stage edge t+2's loads before consuming edge t
  float p_cur = 0.f;
  uint4 dw_cur = make_uint4(0u, 0u, 0u, 0u);
  {
    int j = beg + slot;
    if (j < end){
      int si = srcs[j];
      dw_cur = *(const uint4*)(h + (size_t)si * 256 + hP * 64 + oct * 8);
      float e = lrelu(as[si * 4 + hP] + advP);
      p_cur = __expf(e - mP);
    }
  }
  for (int j0 = beg; j0 < end; j0 += 2){
    int jn = j0 + 2 + slot;
    float p_nxt = 0.f;
    uint4 dw_nxt = make_uint4(0u, 0u, 0u, 0u);
    if (jn < end){
      int si = srcs[jn];
      dw_nxt = *(const uint4*)(h + (size_t)si * 256 + hP * 64 + oct * 8);
      float e = lrelu(as[si * 4 + hP] + advP);
      p_nxt = __expf(e - mP);
    }
    s += p_cur;
    float lo, hi;
    unpack2(dw_cur.x, lo, hi); acc[0] = fmaf(lo, p_cur, acc[0]); acc[1] = fmaf(hi, p_cur, acc[1]);
    unpack2(dw_cur.y, lo, hi); acc[2] = fmaf(lo, p_cur, acc[2]); acc[3] = fmaf(hi, p_cur, acc[3]);
    unpack2(dw_cur.z, lo, hi); acc[4] = fmaf(lo, p_cur, acc[4]); acc[5] = fmaf(hi, p_cur, acc[5]);
    unpack2(dw_cur.w, lo, hi); acc[6] = fmaf(lo, p_cur, acc[6]); acc[7] = fmaf(hi, p_cur, acc[7]);
    p_cur = p_nxt;
    dw_cur = dw_nxt;
  }
  s += __shfl_xor(s, 32);
  #pragma unroll
  for (int i = 0; i < 8; i++) acc[i] += __shfl_xor(acc[i], 32);
  if (lane < 32){
    float inv = 1.f / (s + 1e-16f);
    bf16x8 o;
    #pragma unroll
    for (int i = 0; i < 8; i++){
      float vv = acc[i] * inv + b[lane * 8 + i];
      o[i] = f2bf(vv > 0.f ? vv : 0.f);
    }
    int kt = lane >> 2, g = lane & 3;
    int rt = node >> 4, r = node & 15;
    Ap2[(size_t)(rt * 8 + kt) * 64 + g * 16 + r] = o;
  }
}

// ------- aggregation mu & logstd: interleaved h2, pass-A max, predicated unroll-8 (R18) -------
__global__ __launch_bounds__(128)
void gat_aggr2_k(const int* __restrict__ offs, const int* __restrict__ srcs,
                 const float* __restrict__ as2m, const float* __restrict__ ad2m,
                 const float* __restrict__ as2l, const float* __restrict__ ad2l,
                 const bf16* __restrict__ h2,
                 const float* __restrict__ bmu, const float* __restrict__ bls,
                 float* __restrict__ outmu, float* __restrict__ outls, int n){
  int node = blockIdx.x * 2 + (threadIdx.x >> 6);
  if (node >= n) return;
  int lane = threadIdx.x & 63;
  int beg = offs[node], end = offs[node + 1];
  const float* asA = (lane >= 32) ? as2l : as2m;
  float advA = ((lane >= 32) ? ad2l : ad2m)[node];
  int iA = lane & 31;
  float m = -1e30f;
  for (int j = beg + iA; j < end; j += 32)
    m = fmaxf(m, lrelu(asA[srcs[j]] + advA));
  #pragma unroll
  for (int o = 1; o < 32; o <<= 1) m = fmaxf(m, __shfl_xor(m, o));
  int br = (lane >> 3) & 1, oct = lane & 7, slot = lane >> 4;
  float mP   = __shfl(m, br * 32);
  float advP = __shfl(advA, br * 32);
  const float* asP = br ? as2l : as2m;
  float s = 0.f;
  float acc[8];
  #pragma unroll
  for (int i = 0; i < 8; i++) acc[i] = 0.f;
  #pragma unroll 8
  for (int j0 = beg; j0 < end; j0 += 4){
    int j = j0 + slot;
    if (j < end){
      int si = srcs[j];
      float e = lrelu(asP[si] + advP);
      float p = __expf(e - mP);
      s += p;
      uint4 dw = *(const uint4*)(h2 + (size_t)si * 128 + br * 64 + oct * 8);
      float lo, hi;
      unpack2(dw.x, lo, hi); acc[0] = fmaf(lo, p, acc[0]); acc[1] = fmaf(hi, p, acc[1]);
      unpack2(dw.y, lo, hi); acc[2] = fmaf(lo, p, acc[2]); acc[3] = fmaf(hi, p, acc[3]);
      unpack2(dw.z, lo, hi); acc[4] = fmaf(lo, p, acc[4]); acc[5] = fmaf(hi, p, acc[5]);
      unpack2(dw.w, lo, hi); acc[6] = fmaf(lo, p, acc[6]); acc[7] = fmaf(hi, p, acc[7]);
    }
  }
  #pragma unroll
  for (int off = 16; off <= 32; off <<= 1){
    s += __shfl_xor(s, off);
    #pragma unroll
    for (int i = 0; i < 8; i++) acc[i] += __shfl_xor(acc[i], off);
  }
  if (lane < 16){
    float inv = 1.f / (s + 1e-16f);
    const float* bb = (lane >= 8) ? bls : bmu;
    float* out = (lane >= 8) ? outls : outmu;
    float v[8];
    #pragma unroll
    for (int i = 0; i < 8; i++) v[i] = acc[i] * inv + bb[oct * 8 + i];
    float* op = out + (size_t)node * 64 + oct * 8;
    *(float4*)op       = make_float4(v[0], v[1], v[2], v[3]);
    *(float4*)(op + 4) = make_float4(v[4], v[5], v[6], v[7]);
  }
}

extern "C" void kernel_launch(void* const* d_in, const int* in_sizes, int n_in,
                              void* d_out, int out_size, void* d_ws, size_t ws_size,
                              hipStream_t stream){
  const float* x    = (const float*)d_in[0];
  const int*   ei   = (const int*)d_in[1];
  const float* W1   = (const float*)d_in[2];
  const float* aS1  = (const float*)d_in[3];
  const float* aD1  = (const float*)d_in[4];
  const float* b1   = (const float*)d_in[5];
  const float* Wmu  = (const float*)d_in[6];
  const float* aSmu = (const float*)d_in[7];
  const float* aDmu = (const float*)d_in[8];
  const float* bmu  = (const float*)d_in[9];
  const float* Wls  = (const float*)d_in[10];
  const float* aSls = (const float*)d_in[11];
  const float* aDls = (const float*)d_in[12];
  const float* bls  = (const float*)d_in[13];

  const int N    = NNODES;
  const int E0   = in_sizes[1] / 2;
  const int Etot = E0 + N;

  // ---- workspace layout (float-unit offsets; bf16x8 arrays 16B-aligned) ----
  float* ws = (float*)d_ws;
  bf16x8* Ap2  = (bf16x8*)(ws);                 // [0, 6.4M): layer-1 out, packed A-frag
  bf16*   h1bf = (bf16*)(ws + 6400000);         // [6.4M, 12.8M): 12.8M bf16 row-major
  bf16*   h2   = (bf16*)(ws + 12800000);        // [12.8M, 16M): interleaved [N][128]
  float*  as1  = ws + 16000000;                 // 200K
  float*  ad1  = ws + 16200000;                 // 200K
  float*  as2m = ws + 16400000;                 // 50K each
  float*  ad2m = ws + 16450000;
  float*  as2l = ws + 16500000;
  float*  ad2l = ws + 16550000;
  int*      offs  = (int*)(ws + 16600000);      // 50001
  int*      srcs  = (int*)(ws + 16650016);      // 850000
  unsigned* buck  = (unsigned*)(ws + 17500016); // NB*BCAP = 1028608
  int*      bcnt  = (int*)(ws + 18528640);      // 256
  bf16x8*   Bp1   = (bf16x8*)(ws + 18528912);   // 32768 bf16 (16B-aligned)
  bf16x8*   Bp2   = (bf16x8*)(ws + 18545296);   // 32768 bf16

  float* outmu = (float*)d_out;
  float* outls = (float*)d_out + 3200000;

  const int egrid4 = (Etot + 1023) / 1024;

  // ---- CSR build: single-pass bucket slabs (scan fused into bcsr) ----
  hipMemsetAsync(bcnt, 0, 256 * sizeof(int), stream);
  bscat_k<<<egrid4, 256, 0, stream>>>(ei, E0, Etot, bcnt, buck);
  bcsr_k<<<NB, 256, 0, stream>>>(buck, bcnt, offs, srcs, N, Etot);

  // ---- weight packing for MFMA ----
  cvt_w_k<<<32, 256, 0, stream>>>(W1, Wmu, Wls, Bp1, Bp2);

  // ---- layer 1: GATConv(128 -> 4x64, concat) + bias + ReLU ----
  gemm1_mfma<<<MT, 256, 0, stream>>>(x, Bp1, aS1, aD1, h1bf, as1, ad1);
  gat_aggr1_k<<<(N + 1) / 2, 128, 0, stream>>>(offs, srcs, as1, ad1, h1bf, b1, Ap2, N);

  // ---- layers mu & logstd: GATConv(256 -> 1x64) + bias ----
  gemm2_mfma<<<(MT + 3) / 4, 256, 0, stream>>>(Ap2, Bp2, aSmu, aDmu, aSls, aDls,
                                               h2, as2m, ad2m, as2l, ad2l);
  gat_aggr2_k<<<(N + 1) / 2, 128, 0, stream>>>(offs, srcs, as2m, ad2m, as2l, ad2l,
                                               h2, bmu, bls, outmu, outls, N);
}

// Round 22
// 212.850 us; speedup vs baseline: 1.9358x; 1.0022x over previous
//
#include <hip/hip_runtime.h>
#include <hip/hip_bf16.h>

#define NNODES 50000
#define MT 3125              // NNODES / 16 row-tiles
#define NB 196               // ceil(NNODES / 256) dst-buckets
#define BCAP 5248            // bucket slab capacity (mean 4337, +13 sigma)
typedef __hip_bfloat16 bf16;
typedef __attribute__((ext_vector_type(8))) short bf16x8;  // 8 bf16 (4 VGPRs)
typedef __attribute__((ext_vector_type(4))) float f32x4;   // 4 f32 acc

__device__ __forceinline__ void unpack2(unsigned w, float& lo, float& hi){
  lo = __uint_as_float(w << 16);
  hi = __uint_as_float(w & 0xffff0000u);
}
__device__ __forceinline__ short f2bf(float f){
  union { __hip_bfloat16 h; short s; } u; u.h = __float2bfloat16(f); return u.s;
}
__device__ __forceinline__ float lrelu(float v){ return v > 0.f ? v : 0.2f * v; }

// ------- MFMA GEMM 1 (reads f32 x directly) + fused alpha -------
__global__ __launch_bounds__(256)
void gemm1_mfma(const float* __restrict__ x, const bf16x8* __restrict__ Bp,
                const float* __restrict__ aS, const float* __restrict__ aD,
                bf16* __restrict__ Y, float* __restrict__ as1, float* __restrict__ ad1){
  int rt = blockIdx.x;
  int w = threadIdx.x >> 6, lane = threadIdx.x & 63;
  const float* xr = x + (size_t)(rt * 16 + (lane & 15)) * 128 + (lane >> 4) * 8;
  f32x4 z = {0.f, 0.f, 0.f, 0.f};
  f32x4 acc[4] = {z, z, z, z};
  for (int kt = 0; kt < 4; kt++){
    float4 v0 = *(const float4*)(xr + kt * 32);
    float4 v1 = *(const float4*)(xr + kt * 32 + 4);
    bf16x8 a;
    a[0] = f2bf(v0.x); a[1] = f2bf(v0.y); a[2] = f2bf(v0.z); a[3] = f2bf(v0.w);
    a[4] = f2bf(v1.x); a[5] = f2bf(v1.y); a[6] = f2bf(v1.z); a[7] = f2bf(v1.w);
    #pragma unroll
    for (int c = 0; c < 4; c++){
      bf16x8 b = Bp[(size_t)(kt * 16 + w * 4 + c) * 64 + lane];
      acc[c] = __builtin_amdgcn_mfma_f32_16x16x32_bf16(a, b, acc[c], 0, 0, 0);
    }
  }
  int row0 = rt * 16 + (lane >> 4) * 4;
  #pragma unroll
  for (int c = 0; c < 4; c++){
    int col = w * 64 + c * 16 + (lane & 15);
    #pragma unroll
    for (int i = 0; i < 4; i++)
      Y[(size_t)(row0 + i) * 256 + col] = __float2bfloat16(acc[c][i]);
  }
  float aSv[4], aDv[4];
  #pragma unroll
  for (int c = 0; c < 4; c++){
    int col = c * 16 + (lane & 15);
    aSv[c] = aS[w * 64 + col];
    aDv[c] = aD[w * 64 + col];
  }
  #pragma unroll
  for (int i = 0; i < 4; i++){
    float s1 = 0.f, s2 = 0.f;
    #pragma unroll
    for (int c = 0; c < 4; c++){
      s1 = fmaf(acc[c][i], aSv[c], s1);
      s2 = fmaf(acc[c][i], aDv[c], s2);
    }
    #pragma unroll
    for (int o = 1; o < 16; o <<= 1){
      s1 += __shfl_xor(s1, o);
      s2 += __shfl_xor(s2, o);
    }
    if ((lane & 15) == 0){
      int node = row0 + i;
      as1[node * 4 + w] = s1;
      ad1[node * 4 + w] = s2;
    }
  }
}

// ------- MFMA GEMM 2: one wave = one row-tile, BOTH branches + fused alphas -------
__global__ __launch_bounds__(256)
void gemm2_mfma(const bf16x8* __restrict__ Ap, const bf16x8* __restrict__ Bp,
                const float* __restrict__ aSmu, const float* __restrict__ aDmu,
                const float* __restrict__ aSls, const float* __restrict__ aDls,
                bf16* __restrict__ Y2,
                float* __restrict__ as2m, float* __restrict__ ad2m,
                float* __restrict__ as2l, float* __restrict__ ad2l){
  int w = threadIdx.x >> 6, lane = threadIdx.x & 63;
  int rt = blockIdx.x * 4 + w;
  if (rt >= MT) return;
  f32x4 z = {0.f, 0.f, 0.f, 0.f};
  f32x4 acc[8] = {z, z, z, z, z, z, z, z};   // 0-3 mu, 4-7 ls
  for (int kt = 0; kt < 8; kt++){
    bf16x8 a = Ap[(size_t)(rt * 8 + kt) * 64 + lane];
    #pragma unroll
    for (int c = 0; c < 8; c++){
      bf16x8 b = Bp[(size_t)(kt * 8 + c) * 64 + lane];
      acc[c] = __builtin_amdgcn_mfma_f32_16x16x32_bf16(a, b, acc[c], 0, 0, 0);
    }
  }
  int row0 = rt * 16 + (lane >> 4) * 4;
  #pragma unroll
  for (int c = 0; c < 4; c++){
    int col = c * 16 + (lane & 15);
    #pragma unroll
    for (int i = 0; i < 4; i++){
      Y2[(size_t)(row0 + i) * 128 + col]       = __float2bfloat16(acc[c][i]);
      Y2[(size_t)(row0 + i) * 128 + 64 + col]  = __float2bfloat16(acc[4 + c][i]);
    }
  }
  float aSm[4], aDm[4], aSl[4], aDl[4];
  #pragma unroll
  for (int c = 0; c < 4; c++){
    int col = c * 16 + (lane & 15);
    aSm[c] = aSmu[col]; aDm[c] = aDmu[col];
    aSl[c] = aSls[col]; aDl[c] = aDls[col];
  }
  #pragma unroll
  for (int i = 0; i < 4; i++){
    float s1 = 0.f, s2 = 0.f, s3 = 0.f, s4 = 0.f;
    #pragma unroll
    for (int c = 0; c < 4; c++){
      s1 = fmaf(acc[c][i], aSm[c], s1);
      s2 = fmaf(acc[c][i], aDm[c], s2);
      s3 = fmaf(acc[4 + c][i], aSl[c], s3);
      s4 = fmaf(acc[4 + c][i], aDl[c], s4);
    }
    #pragma unroll
    for (int o = 1; o < 16; o <<= 1){
      s1 += __shfl_xor(s1, o);
      s2 += __shfl_xor(s2, o);
      s3 += __shfl_xor(s3, o);
      s4 += __shfl_xor(s4, o);
    }
    if ((lane & 15) == 0){
      int node = row0 + i;
      as2m[node] = s1; ad2m[node] = s2;
      as2l[node] = s3; ad2l[node] = s4;
    }
  }
}

// ====== single-pass LDS bucket CSR build, with cvt_w fused as extra blocks ======
__global__ __launch_bounds__(256)
void bscat_k(const int* __restrict__ ei, int E0, int Etot,
             int* __restrict__ bcnt, unsigned* __restrict__ buck, int sblocks,
             const float* __restrict__ W1, const float* __restrict__ Wmu,
             const float* __restrict__ Wls, bf16x8* __restrict__ Bp1,
             bf16x8* __restrict__ Bp2){
  if (blockIdx.x >= sblocks){
    // ---- fused weight packing ----
    int t = (blockIdx.x - sblocks) * 256 + threadIdx.x;
    if (t < 4096){
      int lane = t & 63, ct = (t >> 6) & 15, kt = t >> 10;
      int k0 = kt * 32 + (lane >> 4) * 8, col = ct * 16 + (lane & 15);
      bf16x8 o;
      #pragma unroll
      for (int j = 0; j < 8; j++) o[j] = f2bf(W1[(size_t)(k0 + j) * 256 + col]);
      Bp1[t] = o;
    } else if (t < 8192){
      int u = t - 4096;
      int lane = u & 63, ct = (u >> 6) & 7, kt = u >> 9;
      int k0 = kt * 32 + (lane >> 4) * 8, col = ct * 16 + (lane & 15);
      const float* W = (col < 64) ? Wmu : Wls;
      int cc = col & 63;
      bf16x8 o;
      #pragma unroll
      for (int j = 0; j < 8; j++) o[j] = f2bf(W[(size_t)(k0 + j) * 64 + cc]);
      Bp2[u] = o;
    }
    return;
  }
  __shared__ int lh[NB];
  __shared__ int lbase[NB];
  for (int i = threadIdx.x; i < NB; i += 256) lh[i] = 0;
  __syncthreads();
  int base = blockIdx.x * 1024 + threadIdx.x;
  int sA[4], dA[4], rA[4];
  #pragma unroll
  for (int q = 0; q < 4; q++){
    int e = base + q * 256;
    sA[q] = -1;
    if (e < Etot){
      int s, d;
      if (e < E0){ s = ei[e]; d = ei[E0 + e]; } else { s = d = e - E0; }
      sA[q] = s; dA[q] = d;
      rA[q] = atomicAdd(&lh[d >> 8], 1);
    }
  }
  __syncthreads();
  for (int i = threadIdx.x; i < NB; i += 256)
    lbase[i] = lh[i] ? atomicAdd(&bcnt[i], lh[i]) : 0;
  __syncthreads();
  #pragma unroll
  for (int q = 0; q < 4; q++){
    if (sA[q] >= 0){
      int bk = dA[q] >> 8;
      buck[(size_t)bk * BCAP + lbase[bk] + rA[q]] =
          ((unsigned)(dA[q] & 255) << 16) | (unsigned)sA[q];
    }
  }
}

// per-bucket CSR finalize; computes its own bucket-prefix from bcnt (no bscan pass)
__global__ __launch_bounds__(256)
void bcsr_k(const unsigned* __restrict__ buck, const int* __restrict__ bcnt,
            int* __restrict__ offs, int* __restrict__ srcs, int n, int total){
  int b = blockIdx.x;
  __shared__ int eh[256];
  __shared__ int buf[256];
  int t = threadIdx.x;
  int bv = (t < NB) ? bcnt[t] : 0;
  buf[t] = bv; __syncthreads();
  int bacc = bv;
  for (int off = 1; off < 256; off <<= 1){
    int x = (t >= off) ? buf[t - off] : 0;
    __syncthreads();
    bacc += x; buf[t] = bacc; __syncthreads();
  }
  int gbase = (b == 0) ? 0 : buf[b - 1];
  int cntb  = bcnt[b];
  const unsigned* slab = buck + (size_t)b * BCAP;
  __syncthreads();
  eh[t] = 0;
  __syncthreads();
  for (int j = t; j < cntb; j += 256)
    atomicAdd(&eh[(slab[j] >> 16) & 255], 1);
  __syncthreads();
  int v = eh[t];
  buf[t] = v; __syncthreads();
  int acc = v;
  for (int off = 1; off < 256; off <<= 1){
    int x = (t >= off) ? buf[t - off] : 0;
    __syncthreads();
    acc += x; buf[t] = acc; __syncthreads();
  }
  int loff = acc - v;
  int node = b * 256 + t;
  if (node < n) offs[node] = gbase + loff;
  if (b == NB - 1 && t == 0) offs[n] = total;
  __syncthreads();
  eh[t] = loff;
  __syncthreads();
  for (int j = t; j < cntb; j += 256){
    unsigned val = slab[j];
    int dlo = (val >> 16) & 255;
    int rank = atomicAdd(&eh[dlo], 1);
    srcs[gbase + rank] = (int)(val & 0xffffu);
  }
}

// ------- aggregation layer 1: persistent grid-stride, pass-A max, predicated pass 2 -------
__global__ __launch_bounds__(128)
void gat_aggr1_k(const int* __restrict__ offs, const int* __restrict__ srcs,
                 const float* __restrict__ as, const float* __restrict__ ad,
                 const bf16* __restrict__ h, const float* __restrict__ b,
                 bf16x8* __restrict__ Ap2, int n){
  int lane = threadIdx.x & 63;
  int hA = lane >> 4, iA = lane & 15;
  int hP = (lane >> 3) & 3, oct = lane & 7, slot = lane >> 5;
  for (int node = blockIdx.x * 2 + (threadIdx.x >> 6); node < n; node += gridDim.x * 2){
    int beg = offs[node], end = offs[node + 1];
    float advA = ad[node * 4 + hA];
    float m = -1e30f;
    for (int j = beg + iA; j < end; j += 16)
      m = fmaxf(m, lrelu(as[srcs[j] * 4 + hA] + advA));
    #pragma unroll
    for (int o = 1; o < 16; o <<= 1) m = fmaxf(m, __shfl_xor(m, o));
    float mP   = __shfl(m, hP * 16);
    float advP = __shfl(advA, hP * 16);
    float s = 0.f;
    float acc[8];
    #pragma unroll
    for (int i = 0; i < 8; i++) acc[i] = 0.f;
    #pragma unroll 8
    for (int j0 = beg; j0 < end; j0 += 2){
      int j = j0 + slot;
      if (j < end){
        int si = srcs[j];
        float e = lrelu(as[si * 4 + hP] + advP);
        float p = __expf(e - mP);
        s += p;
        uint4 dw = *(const uint4*)(h + (size_t)si * 256 + hP * 64 + oct * 8);
        float lo, hi;
        unpack2(dw.x, lo, hi); acc[0] = fmaf(lo, p, acc[0]); acc[1] = fmaf(hi, p, acc[1]);
        unpack2(dw.y, lo, hi); acc[2] = fmaf(lo, p, acc[2]); acc[3] = fmaf(hi, p, acc[3]);
        unpack2(dw.z, lo, hi); acc[4] = fmaf(lo, p, acc[4]); acc[5] = fmaf(hi, p, acc[5]);
        unpack2(dw.w, lo, hi); acc[6] = fmaf(lo, p, acc[6]); acc[7] = fmaf(hi, p, acc[7]);
      }
    }
    s += __shfl_xor(s, 32);
    #pragma unroll
    for (int i = 0; i < 8; i++) acc[i] += __shfl_xor(acc[i], 32);
    if (lane < 32){
      float inv = 1.f / (s + 1e-16f);
      bf16x8 o;
      #pragma unroll
      for (int i = 0; i < 8; i++){
        float vv = acc[i] * inv + b[lane * 8 + i];
        o[i] = f2bf(vv > 0.f ? vv : 0.f);
      }
      int kt = lane >> 2, g = lane & 3;
      int rt = node >> 4, r = node & 15;
      Ap2[(size_t)(rt * 8 + kt) * 64 + g * 16 + r] = o;
    }
  }
}

// ------- aggregation mu & logstd: persistent grid-stride, interleaved h2 -------
__global__ __launch_bounds__(128)
void gat_aggr2_k(const int* __restrict__ offs, const int* __restrict__ srcs,
                 const float* __restrict__ as2m, const float* __restrict__ ad2m,
                 const float* __restrict__ as2l, const float* __restrict__ ad2l,
                 const bf16* __restrict__ h2,
                 const float* __restrict__ bmu, const float* __restrict__ bls,
                 float* __restrict__ outmu, float* __restrict__ outls, int n){
  int lane = threadIdx.x & 63;
  int iA = lane & 31;
  int br = (lane >> 3) & 1, oct = lane & 7, slot = lane >> 4;
  const float* asA = (lane >= 32) ? as2l : as2m;
  const float* adA = (lane >= 32) ? ad2l : ad2m;
  const float* asP = br ? as2l : as2m;
  for (int node = blockIdx.x * 2 + (threadIdx.x >> 6); node < n; node += gridDim.x * 2){
    int beg = offs[node], end = offs[node + 1];
    float advA = adA[node];
    float m = -1e30f;
    for (int j = beg + iA; j < end; j += 32)
      m = fmaxf(m, lrelu(asA[srcs[j]] + advA));
    #pragma unroll
    for (int o = 1; o < 32; o <<= 1) m = fmaxf(m, __shfl_xor(m, o));
    float mP   = __shfl(m, br * 32);
    float advP = __shfl(advA, br * 32);
    float s = 0.f;
    float acc[8];
    #pragma unroll
    for (int i = 0; i < 8; i++) acc[i] = 0.f;
    #pragma unroll 8
    for (int j0 = beg; j0 < end; j0 += 4){
      int j = j0 + slot;
      if (j < end){
        int si = srcs[j];
        float e = lrelu(asP[si] + advP);
        float p = __expf(e - mP);
        s += p;
        uint4 dw = *(const uint4*)(h2 + (size_t)si * 128 + br * 64 + oct * 8);
        float lo, hi;
        unpack2(dw.x, lo, hi); acc[0] = fmaf(lo, p, acc[0]); acc[1] = fmaf(hi, p, acc[1]);
        unpack2(dw.y, lo, hi); acc[2] = fmaf(lo, p, acc[2]); acc[3] = fmaf(hi, p, acc[3]);
        unpack2(dw.z, lo, hi); acc[4] = fmaf(lo, p, acc[4]); acc[5] = fmaf(hi, p, acc[5]);
        unpack2(dw.w, lo, hi); acc[6] = fmaf(lo, p, acc[6]); acc[7] = fmaf(hi, p, acc[7]);
      }
    }
    #pragma unroll
    for (int off = 16; off <= 32; off <<= 1){
      s += __shfl_xor(s, off);
      #pragma unroll
      for (int i = 0; i < 8; i++) acc[i] += __shfl_xor(acc[i], off);
    }
    if (lane < 16){
      float inv = 1.f / (s + 1e-16f);
      const float* bb = (lane >= 8) ? bls : bmu;
      float* out = (lane >= 8) ? outls : outmu;
      float v[8];
      #pragma unroll
      for (int i = 0; i < 8; i++) v[i] = acc[i] * inv + bb[oct * 8 + i];
      float* op = out + (size_t)node * 64 + oct * 8;
      *(float4*)op       = make_float4(v[0], v[1], v[2], v[3]);
      *(float4*)(op + 4) = make_float4(v[4], v[5], v[6], v[7]);
    }
  }
}

extern "C" void kernel_launch(void* const* d_in, const int* in_sizes, int n_in,
                              void* d_out, int out_size, void* d_ws, size_t ws_size,
                              hipStream_t stream){
  const float* x    = (const float*)d_in[0];
  const int*   ei   = (const int*)d_in[1];
  const float* W1   = (const float*)d_in[2];
  const float* aS1  = (const float*)d_in[3];
  const float* aD1  = (const float*)d_in[4];
  const float* b1   = (const float*)d_in[5];
  const float* Wmu  = (const float*)d_in[6];
  const float* aSmu = (const float*)d_in[7];
  const float* aDmu = (const float*)d_in[8];
  const float* bmu  = (const float*)d_in[9];
  const float* Wls  = (const float*)d_in[10];
  const float* aSls = (const float*)d_in[11];
  const float* aDls = (const float*)d_in[12];
  const float* bls  = (const float*)d_in[13];

  const int N    = NNODES;
  const int E0   = in_sizes[1] / 2;
  const int Etot = E0 + N;

  // ---- workspace layout (float-unit offsets; bf16x8 arrays 16B-aligned) ----
  float* ws = (float*)d_ws;
  bf16x8* Ap2  = (bf16x8*)(ws);                 // [0, 6.4M): layer-1 out, packed A-frag
  bf16*   h1bf = (bf16*)(ws + 6400000);         // [6.4M, 12.8M): 12.8M bf16 row-major
  bf16*   h2   = (bf16*)(ws + 12800000);        // [12.8M, 16M): interleaved [N][128]
  float*  as1  = ws + 16000000;                 // 200K
  float*  ad1  = ws + 16200000;                 // 200K
  float*  as2m = ws + 16400000;                 // 50K each
  float*  ad2m = ws + 16450000;
  float*  as2l = ws + 16500000;
  float*  ad2l = ws + 16550000;
  int*      offs  = (int*)(ws + 16600000);      // 50001
  int*      srcs  = (int*)(ws + 16650016);      // 850000
  unsigned* buck  = (unsigned*)(ws + 17500016); // NB*BCAP = 1028608
  int*      bcnt  = (int*)(ws + 18528640);      // 256
  bf16x8*   Bp1   = (bf16x8*)(ws + 18528912);   // 32768 bf16 (16B-aligned)
  bf16x8*   Bp2   = (bf16x8*)(ws + 18545296);   // 32768 bf16

  float* outmu = (float*)d_out;
  float* outls = (float*)d_out + 3200000;

  const int egrid4 = (Etot + 1023) / 1024;

  // ---- CSR build (cvt_w fused as trailing blocks) ----
  hipMemsetAsync(bcnt, 0, 256 * sizeof(int), stream);
  bscat_k<<<egrid4 + 32, 256, 0, stream>>>(ei, E0, Etot, bcnt, buck, egrid4,
                                           W1, Wmu, Wls, Bp1, Bp2);
  bcsr_k<<<NB, 256, 0, stream>>>(buck, bcnt, offs, srcs, N, Etot);

  // ---- layer 1: GATConv(128 -> 4x64, concat) + bias + ReLU ----
  gemm1_mfma<<<MT, 256, 0, stream>>>(x, Bp1, aS1, aD1, h1bf, as1, ad1);
  gat_aggr1_k<<<4096, 128, 0, stream>>>(offs, srcs, as1, ad1, h1bf, b1, Ap2, N);

  // ---- layers mu & logstd: GATConv(256 -> 1x64) + bias ----
  gemm2_mfma<<<(MT + 3) / 4, 256, 0, stream>>>(Ap2, Bp2, aSmu, aDmu, aSls, aDls,
                                               h2, as2m, ad2m, as2l, ad2l);
  gat_aggr2_k<<<4096, 128, 0, stream>>>(offs, srcs, as2m, ad2m, as2l, ad2l,
                                        h2, bmu, bls, outmu, outls, N);
}